// Round 1
// baseline (2346.217 us; speedup 1.0000x reference)
//
#include <hip/hip_runtime.h>
#include <math.h>

// Problem constants
#define B   16
#define N   128
#define E   4
#define H   64
#define M   64
#define IN_ 32
#define T   32
#define K1  128   // edge MLP layer1 width
#define K2  256   // edge MLP layer2 width
#define K3  128   // edge MLP layer3 width (f feature dim)

// -------------------------------------------------------------------------
// h = pad(h_in) to [B,N,H]
__global__ __launch_bounds__(256) void pad_h_kernel(const float* __restrict__ h_in,
                                                    float* __restrict__ h) {
    int idx = blockIdx.x * 256 + threadIdx.x;   // over B*N*H
    if (idx >= B * N * H) return;
    int i  = idx & (H - 1);
    int bn = idx >> 6;
    h[idx] = (i < IN_) ? h_in[bn * IN_ + i] : 0.f;
}

// -------------------------------------------------------------------------
// Edge MLP: f = relu(relu(relu(am@We0+be0)@We1+be1)@We2+be2), fused per 32-edge tile
__global__ __launch_bounds__(256) void edge_mlp_kernel(
    const float* __restrict__ am,
    const float* __restrict__ We0, const float* __restrict__ be0,
    const float* __restrict__ We1, const float* __restrict__ be1,
    const float* __restrict__ We2, const float* __restrict__ be2,
    float* __restrict__ f) {
    __shared__ float x_lds[32][E];      // 0.5 KB
    __shared__ float y1_lds[32][K1];    // 16 KB
    __shared__ float y2_lds[32][K2];    // 32 KB
    int tid = threadIdx.x;
    long long g0 = (long long)blockIdx.x * 32;   // first edge of tile

    // P0: load 32 edges x 4 features (fully coalesced)
    if (tid < 32 * E) ((float*)x_lds)[tid] = am[g0 * E + tid];
    __syncthreads();

    // P1: y1[e][j], j = tid&127, e-range by half-block
    {
        int j  = tid & 127;
        int e0 = (tid >> 7) * 16;
        float w0 = We0[0 * K1 + j], w1 = We0[1 * K1 + j];
        float w2 = We0[2 * K1 + j], w3 = We0[3 * K1 + j];
        float bb = be0[j];
        #pragma unroll
        for (int e = 0; e < 16; ++e) {
            float v = bb + x_lds[e0 + e][0] * w0 + x_lds[e0 + e][1] * w1
                         + x_lds[e0 + e][2] * w2 + x_lds[e0 + e][3] * w3;
            y1_lds[e0 + e][j] = fmaxf(v, 0.f);
        }
    }
    __syncthreads();

    // P2: y2[e][j], thread owns column j = tid, 32 e-accumulators
    {
        int j = tid;
        float acc[32];
        float bb = be1[j];
        #pragma unroll
        for (int e = 0; e < 32; ++e) acc[e] = bb;
        for (int k0 = 0; k0 < K1; k0 += 8) {
            float w[8];
            #pragma unroll
            for (int kk = 0; kk < 8; ++kk) w[kk] = We1[(k0 + kk) * K2 + j];
            #pragma unroll
            for (int e = 0; e < 32; ++e) {
                const float4* yr = (const float4*)&y1_lds[e][k0];
                float4 ya = yr[0], yb = yr[1];
                acc[e] += ya.x * w[0] + ya.y * w[1] + ya.z * w[2] + ya.w * w[3]
                        + yb.x * w[4] + yb.y * w[5] + yb.z * w[6] + yb.w * w[7];
            }
        }
        #pragma unroll
        for (int e = 0; e < 32; ++e) y2_lds[e][j] = fmaxf(acc[e], 0.f);
    }
    __syncthreads();

    // P3: f[e][j], j = tid&127, 16 e's per thread
    {
        int j  = tid & 127;
        int e0 = (tid >> 7) * 16;
        float acc[16];
        float bb = be2[j];
        #pragma unroll
        for (int e = 0; e < 16; ++e) acc[e] = bb;
        for (int k0 = 0; k0 < K2; k0 += 8) {
            float w[8];
            #pragma unroll
            for (int kk = 0; kk < 8; ++kk) w[kk] = We2[(k0 + kk) * K3 + j];
            #pragma unroll
            for (int e = 0; e < 16; ++e) {
                const float4* yr = (const float4*)&y2_lds[e0 + e][k0];
                float4 ya = yr[0], yb = yr[1];
                acc[e] += ya.x * w[0] + ya.y * w[1] + ya.z * w[2] + ya.w * w[3]
                        + yb.x * w[4] + yb.y * w[5] + yb.z * w[6] + yb.w * w[7];
            }
        }
        #pragma unroll
        for (int e = 0; e < 16; ++e)
            f[(g0 + e0 + e) * K3 + j] = fmaxf(acc[e], 0.f);
    }
}

// -------------------------------------------------------------------------
// msg[b,v,:] : t = einsum('bvwk,bwi->bvki', f, h); msg = einsum('bvki,koi->bvo',t,W3)
//              + einsum('oi,bi->bo', b3, h.sum(1))
// One block per (b,v). h-tile LDS buffer reused for t.
__global__ __launch_bounds__(256) void msg_kernel(
    const float* __restrict__ f, const float* __restrict__ h,
    const float* __restrict__ We3, const float* __restrict__ be3,
    float* __restrict__ msg) {
    __shared__ float hl[N][H];     // 32 KB; h then reused for t
    __shared__ float hsum[H];
    __shared__ float red[256];
    int tid = threadIdx.x;
    int bv  = blockIdx.x;
    int b   = bv >> 7;

    const float* hb = h + b * N * H;
    for (int idx = tid; idx < N * H; idx += 256) ((float*)hl)[idx] = hb[idx];
    __syncthreads();
    if (tid < H) {
        float s = 0.f;
        for (int w = 0; w < N; ++w) s += hl[w][tid];
        hsum[tid] = s;
    }
    __syncthreads();

    // t-phase: thread (i = tid&63, k-range kr = (tid>>6)*32)
    int i  = tid & 63;
    int kr = (tid >> 6) * 32;
    float acc[32];
    #pragma unroll
    for (int kk = 0; kk < 32; ++kk) acc[kk] = 0.f;
    const float* fbv = f + (long long)bv * N * K3;
    for (int w = 0; w < N; ++w) {
        float hv = hl[w][i];
        const float4* fr = (const float4*)(fbv + w * K3 + kr);
        #pragma unroll
        for (int q4 = 0; q4 < 8; ++q4) {
            float4 fv = fr[q4];
            acc[q4 * 4 + 0] += fv.x * hv;
            acc[q4 * 4 + 1] += fv.y * hv;
            acc[q4 * 4 + 2] += fv.z * hv;
            acc[q4 * 4 + 3] += fv.w * hv;
        }
    }
    __syncthreads();   // all h reads done
    #pragma unroll
    for (int kk = 0; kk < 32; ++kk) hl[kr + kk][i] = acc[kk];  // t[k][i]
    __syncthreads();

    // msg-phase: o = tid>>2, i-range i0 = (tid&3)*16
    int o  = tid >> 2;
    int i0 = (tid & 3) * 16;
    float s = 0.f;
    for (int k = 0; k < K3; ++k) {
        const float4* tr = (const float4*)&hl[k][i0];
        const float4* wr = (const float4*)(We3 + k * (M * H) + o * H + i0);
        #pragma unroll
        for (int q4 = 0; q4 < 4; ++q4) {
            float4 tv = tr[q4];
            float4 wv = wr[q4];
            s += tv.x * wv.x + tv.y * wv.y + tv.z * wv.z + tv.w * wv.w;
        }
    }
    if ((tid & 3) == 0) {   // bias term: sum_i be3[o*64+i]*hsum[i]
        #pragma unroll 4
        for (int i2 = 0; i2 < H; ++i2) s += be3[o * H + i2] * hsum[i2];
    }
    red[tid] = s;
    __syncthreads();
    if ((tid & 3) == 0)
        msg[bv * M + o] = red[tid] + red[tid + 1] + red[tid + 2] + red[tid + 3];
}

// -------------------------------------------------------------------------
// torch-style single-step GRU + mask. One block per (b,v), in-place h update.
__global__ __launch_bounds__(192) void gru_kernel(
    const float* __restrict__ msg, float* __restrict__ h,
    const float* __restrict__ Wih, const float* __restrict__ Whh,
    const float* __restrict__ bih, const float* __restrict__ bhh,
    const int* __restrict__ g_size) {
    __shared__ float m_lds[M];
    __shared__ float h_lds[H];
    __shared__ float gi[3 * H], gh[3 * H];
    int tid = threadIdx.x;
    int bv  = blockIdx.x;
    int b = bv >> 7, v = bv & 127;

    if (tid < M) m_lds[tid] = msg[bv * M + tid];
    else if (tid < M + H) h_lds[tid - M] = h[bv * H + (tid - M)];
    __syncthreads();

    {
        float si = bih[tid], sh = bhh[tid];
        const float* wi = Wih + tid * M;
        const float* wh = Whh + tid * H;
        #pragma unroll 4
        for (int k = 0; k < M; ++k) si += wi[k] * m_lds[k];
        #pragma unroll 4
        for (int k = 0; k < H; ++k) sh += wh[k] * h_lds[k];
        gi[tid] = si;
        gh[tid] = sh;
    }
    __syncthreads();
    if (tid < H) {
        float r = 1.f / (1.f + expf(-(gi[tid] + gh[tid])));
        float z = 1.f / (1.f + expf(-(gi[H + tid] + gh[H + tid])));
        float n = tanhf(gi[2 * H + tid] + r * gh[2 * H + tid]);
        float hv = (1.f - z) * n + z * h_lds[tid];
        float maskf = (v < g_size[b]) ? 1.f : 0.f;
        h[bv * H + tid] = hv * maskf;
    }
}

// -------------------------------------------------------------------------
// Readout: contrib[b,v,:] = mask * sigmoid(MLP_i([h,h_in])) * MLP_j(h)
__global__ __launch_bounds__(256) void readout_kernel(
    const float* __restrict__ h, const float* __restrict__ h_in,
    const int* __restrict__ g_size,
    const float* __restrict__ Wi0, const float* __restrict__ bi0,
    const float* __restrict__ Wi1, const float* __restrict__ bi1,
    const float* __restrict__ Wi2, const float* __restrict__ bi2,
    const float* __restrict__ Wi3, const float* __restrict__ bi3,
    const float* __restrict__ Wj0, const float* __restrict__ bj0,
    const float* __restrict__ Wj1, const float* __restrict__ bj1,
    const float* __restrict__ Wj2, const float* __restrict__ bj2,
    const float* __restrict__ Wj3, const float* __restrict__ bj3,
    float* __restrict__ contrib) {
    __shared__ float x[H + IN_];
    __shared__ float a1[128], a2[256], a3[128];
    __shared__ float gate[T];
    int tid = threadIdx.x;
    int bv  = blockIdx.x;
    int b = bv >> 7, v = bv & 127;

    if (tid < H) x[tid] = h[bv * H + tid];
    else if (tid < H + IN_) x[tid] = h_in[bv * IN_ + (tid - H)];
    __syncthreads();

    // ---- MLP_i on x[0:96]
    if (tid < 128) {
        float s = bi0[tid];
        #pragma unroll 4
        for (int c = 0; c < 96; ++c) s += x[c] * Wi0[c * 128 + tid];
        a1[tid] = fmaxf(s, 0.f);
    }
    __syncthreads();
    {
        float s = bi1[tid];
        #pragma unroll 4
        for (int k = 0; k < 128; ++k) s += a1[k] * Wi1[k * 256 + tid];
        a2[tid] = fmaxf(s, 0.f);
    }
    __syncthreads();
    if (tid < 128) {
        float s = bi2[tid];
        #pragma unroll 4
        for (int k = 0; k < 256; ++k) s += a2[k] * Wi2[k * 128 + tid];
        a3[tid] = fmaxf(s, 0.f);
    }
    __syncthreads();
    if (tid < T) {
        float s = bi3[tid];
        #pragma unroll 4
        for (int k = 0; k < 128; ++k) s += a3[k] * Wi3[k * T + tid];
        gate[tid] = 1.f / (1.f + expf(-s));
    }
    __syncthreads();

    // ---- MLP_j on x[0:64] (reuse a1,a2,a3)
    if (tid < 128) {
        float s = bj0[tid];
        #pragma unroll 4
        for (int c = 0; c < 64; ++c) s += x[c] * Wj0[c * 128 + tid];
        a1[tid] = fmaxf(s, 0.f);
    }
    __syncthreads();
    {
        float s = bj1[tid];
        #pragma unroll 4
        for (int k = 0; k < 128; ++k) s += a1[k] * Wj1[k * 256 + tid];
        a2[tid] = fmaxf(s, 0.f);
    }
    __syncthreads();
    if (tid < 128) {
        float s = bj2[tid];
        #pragma unroll 4
        for (int k = 0; k < 256; ++k) s += a2[k] * Wj2[k * 128 + tid];
        a3[tid] = fmaxf(s, 0.f);
    }
    __syncthreads();
    if (tid < T) {
        float s = bj3[tid];
        #pragma unroll 4
        for (int k = 0; k < 128; ++k) s += a3[k] * Wj3[k * T + tid];
        float maskf = (v < g_size[b]) ? 1.f : 0.f;
        contrib[bv * T + tid] = maskf * gate[tid] * s;
    }
}

// -------------------------------------------------------------------------
// res[b,:] = sum_v contrib[b,v,:]; out = log_softmax(res)
__global__ __launch_bounds__(64) void finalize_kernel(const float* __restrict__ contrib,
                                                      float* __restrict__ out) {
    __shared__ float res[T];
    int b = blockIdx.x;
    int o = threadIdx.x;
    if (o < T) {
        float s = 0.f;
        for (int v = 0; v < N; ++v) s += contrib[(b * N + v) * T + o];
        res[o] = s;
    }
    __syncthreads();
    if (o < T) {
        float mx = res[0];
        for (int i = 1; i < T; ++i) mx = fmaxf(mx, res[i]);
        float se = 0.f;
        for (int i = 0; i < T; ++i) se += expf(res[i] - mx);
        out[b * T + o] = res[o] - mx - logf(se);
    }
}

// -------------------------------------------------------------------------
extern "C" void kernel_launch(void* const* d_in, const int* in_sizes, int n_in,
                              void* d_out, int out_size, void* d_ws, size_t ws_size,
                              hipStream_t stream) {
    (void)in_sizes; (void)n_in; (void)out_size; (void)ws_size;
    const float* h_in = (const float*)d_in[0];
    const float* am   = (const float*)d_in[1];
    const int*   g_sz = (const int*)d_in[2];
    const float* We0 = (const float*)d_in[3],  *be0 = (const float*)d_in[4];
    const float* We1 = (const float*)d_in[5],  *be1 = (const float*)d_in[6];
    const float* We2 = (const float*)d_in[7],  *be2 = (const float*)d_in[8];
    const float* We3 = (const float*)d_in[9],  *be3 = (const float*)d_in[10];
    const float* Wih = (const float*)d_in[11], *Whh = (const float*)d_in[12];
    const float* bih = (const float*)d_in[13], *bhh = (const float*)d_in[14];
    const float* Wi0 = (const float*)d_in[15], *bi0 = (const float*)d_in[16];
    const float* Wj0 = (const float*)d_in[17], *bj0 = (const float*)d_in[18];
    const float* Wi1 = (const float*)d_in[19], *bi1 = (const float*)d_in[20];
    const float* Wj1 = (const float*)d_in[21], *bj1 = (const float*)d_in[22];
    const float* Wi2 = (const float*)d_in[23], *bi2 = (const float*)d_in[24];
    const float* Wj2 = (const float*)d_in[25], *bj2 = (const float*)d_in[26];
    const float* Wi3 = (const float*)d_in[27], *bi3 = (const float*)d_in[28];
    const float* Wj3 = (const float*)d_in[29], *bj3 = (const float*)d_in[30];

    float* f       = (float*)d_ws;                       // 33554432 floats (128 MB)
    float* h       = f + (size_t)B * N * N * K3;         // 131072
    float* msg     = h + (size_t)B * N * H;              // 131072
    float* contrib = msg + (size_t)B * N * M;            // 65536
    float* out     = (float*)d_out;

    pad_h_kernel<<<(B * N * H) / 256, 256, 0, stream>>>(h_in, h);
    edge_mlp_kernel<<<(B * N * N) / 32, 256, 0, stream>>>(am, We0, be0, We1, be1,
                                                          We2, be2, f);
    for (int l = 0; l < 3; ++l) {
        msg_kernel<<<B * N, 256, 0, stream>>>(f, h, We3, be3, msg);
        gru_kernel<<<B * N, 192, 0, stream>>>(msg, h, Wih, Whh, bih, bhh, g_sz);
    }
    readout_kernel<<<B * N, 256, 0, stream>>>(h, h_in, g_sz,
                                              Wi0, bi0, Wi1, bi1, Wi2, bi2, Wi3, bi3,
                                              Wj0, bj0, Wj1, bj1, Wj2, bj2, Wj3, bj3,
                                              contrib);
    finalize_kernel<<<B, 64, 0, stream>>>(contrib, out);
}

// Round 2
// 1609.520 us; speedup vs baseline: 1.4577x; 1.4577x over previous
//
#include <hip/hip_runtime.h>
#include <hip/hip_bf16.h>
#include <math.h>

// Problem constants
#define B   16
#define N   128
#define E   4
#define H   64
#define M   64
#define IN_ 32
#define T   32
#define K1  128   // edge MLP layer1 width
#define K2  256   // edge MLP layer2 width
#define K3  128   // edge MLP layer3 width (f feature dim)

// bf16 helpers -------------------------------------------------------------
__device__ __forceinline__ float bf_lo(unsigned u) {
    return __uint_as_float(u << 16);
}
__device__ __forceinline__ float bf_hi(unsigned u) {
    return __uint_as_float(u & 0xffff0000u);
}
__device__ __forceinline__ unsigned pack_bf2(float a, float b) {
    union { __hip_bfloat162 v; unsigned u; } c;
    c.v.x = __float2bfloat16(a);
    c.v.y = __float2bfloat16(b);
    return c.u;
}

// -------------------------------------------------------------------------
// h = pad(h_in) to [B,N,H]
__global__ __launch_bounds__(256) void pad_h_kernel(const float* __restrict__ h_in,
                                                    float* __restrict__ h) {
    int idx = blockIdx.x * 256 + threadIdx.x;   // over B*N*H
    if (idx >= B * N * H) return;
    int i  = idx & (H - 1);
    int bn = idx >> 6;
    h[idx] = (i < IN_) ? h_in[bn * IN_ + i] : 0.f;
}

// -------------------------------------------------------------------------
// Edge MLP: f = relu(relu(relu(am@We0+be0)@We1+be1)@We2+be2), fused per 32-edge
// tile; output stored bf16.
__global__ __launch_bounds__(256) void edge_mlp_kernel(
    const float* __restrict__ am,
    const float* __restrict__ We0, const float* __restrict__ be0,
    const float* __restrict__ We1, const float* __restrict__ be1,
    const float* __restrict__ We2, const float* __restrict__ be2,
    __hip_bfloat16* __restrict__ f) {
    __shared__ float x_lds[32][E];      // 0.5 KB
    __shared__ float y1_lds[32][K1];    // 16 KB
    __shared__ float y2_lds[32][K2];    // 32 KB
    int tid = threadIdx.x;
    long long g0 = (long long)blockIdx.x * 32;   // first edge of tile

    if (tid < 32 * E) ((float*)x_lds)[tid] = am[g0 * E + tid];
    __syncthreads();

    // P1: y1[e][j]
    {
        int j  = tid & 127;
        int e0 = (tid >> 7) * 16;
        float w0 = We0[0 * K1 + j], w1 = We0[1 * K1 + j];
        float w2 = We0[2 * K1 + j], w3 = We0[3 * K1 + j];
        float bb = be0[j];
        #pragma unroll
        for (int e = 0; e < 16; ++e) {
            float v = bb + x_lds[e0 + e][0] * w0 + x_lds[e0 + e][1] * w1
                         + x_lds[e0 + e][2] * w2 + x_lds[e0 + e][3] * w3;
            y1_lds[e0 + e][j] = fmaxf(v, 0.f);
        }
    }
    __syncthreads();

    // P2: y2[e][j]
    {
        int j = tid;
        float acc[32];
        float bb = be1[j];
        #pragma unroll
        for (int e = 0; e < 32; ++e) acc[e] = bb;
        for (int k0 = 0; k0 < K1; k0 += 8) {
            float w[8];
            #pragma unroll
            for (int kk = 0; kk < 8; ++kk) w[kk] = We1[(k0 + kk) * K2 + j];
            #pragma unroll
            for (int e = 0; e < 32; ++e) {
                const float4* yr = (const float4*)&y1_lds[e][k0];
                float4 ya = yr[0], yb = yr[1];
                acc[e] += ya.x * w[0] + ya.y * w[1] + ya.z * w[2] + ya.w * w[3]
                        + yb.x * w[4] + yb.y * w[5] + yb.z * w[6] + yb.w * w[7];
            }
        }
        #pragma unroll
        for (int e = 0; e < 32; ++e) y2_lds[e][j] = fmaxf(acc[e], 0.f);
    }
    __syncthreads();

    // P3: f[e][j] -> bf16
    {
        int j  = tid & 127;
        int e0 = (tid >> 7) * 16;
        float acc[16];
        float bb = be2[j];
        #pragma unroll
        for (int e = 0; e < 16; ++e) acc[e] = bb;
        for (int k0 = 0; k0 < K2; k0 += 8) {
            float w[8];
            #pragma unroll
            for (int kk = 0; kk < 8; ++kk) w[kk] = We2[(k0 + kk) * K3 + j];
            #pragma unroll
            for (int e = 0; e < 16; ++e) {
                const float4* yr = (const float4*)&y2_lds[e0 + e][k0];
                float4 ya = yr[0], yb = yr[1];
                acc[e] += ya.x * w[0] + ya.y * w[1] + ya.z * w[2] + ya.w * w[3]
                        + yb.x * w[4] + yb.y * w[5] + yb.z * w[6] + yb.w * w[7];
            }
        }
        #pragma unroll
        for (int e = 0; e < 16; ++e)
            f[(g0 + e0 + e) * K3 + j] = __float2bfloat16(fmaxf(acc[e], 0.f));
    }
}

// -------------------------------------------------------------------------
// msg_init: msg[b,v,o] = bias[b,o] = sum_i be3[o*64+i] * hsum[b,i]
__global__ __launch_bounds__(256) void msg_init_kernel(
    const float* __restrict__ h, const float* __restrict__ be3,
    float* __restrict__ msg) {
    __shared__ float part[4][64];
    __shared__ float hsum[64];
    __shared__ float bias[64];
    int tid = threadIdx.x;
    int b = blockIdx.x;
    int i = tid & 63, wq = tid >> 6;
    float s = 0.f;
    for (int w = wq; w < N; w += 4) s += h[((size_t)(b * N + w)) * H + i];
    part[wq][i] = s;
    __syncthreads();
    if (tid < 64) hsum[tid] = part[0][tid] + part[1][tid] + part[2][tid] + part[3][tid];
    __syncthreads();
    if (tid < 64) {
        float sb = 0.f;
        #pragma unroll 4
        for (int ii = 0; ii < H; ++ii) sb += be3[tid * H + ii] * hsum[ii];
        bias[tid] = sb;
    }
    __syncthreads();
    for (int idx = tid; idx < N * M; idx += 256)
        msg[(size_t)b * N * M + idx] = bias[idx & 63];
}

// -------------------------------------------------------------------------
// Kernel A: P[b,w,kap] = sum_i h[b,w,i] * We3[kap*64 + i], kap = k*64+o.
// We3 row is wave-uniform (readfirstlane) -> scalar/L1 path; h row in regs.
// Output bf16.
__global__ __launch_bounds__(256) void compute_P_kernel(
    const float* __restrict__ h, const float* __restrict__ We3,
    __hip_bfloat16* __restrict__ P) {
    int tid = threadIdx.x;
    int kot = blockIdx.x;          // 0..63 : kap tile of 128
    int bwt = blockIdx.y;          // 0..31 : row tile of 64
    int rg = tid & 63;             // row within tile
    int pg = tid >> 6;             // 0..3  : 32 kap each

    size_t bw = (size_t)bwt * 64 + rg;
    const float4* hrow = (const float4*)(h + bw * H);
    float4 hr[16];
    #pragma unroll
    for (int ic = 0; ic < 16; ++ic) hr[ic] = hrow[ic];

    float acc[32];
    #pragma unroll
    for (int q = 0; q < 32; ++q) acc[q] = 0.f;

    int kap0 = kot * 128 + pg * 32;
    for (int q = 0; q < 32; ++q) {
        int off = __builtin_amdgcn_readfirstlane((kap0 + q) << 6);  // kap*64
        const float4* wrow = (const float4*)(We3 + off);
        float s = 0.f;
        #pragma unroll
        for (int ic = 0; ic < 16; ++ic) {
            float4 w4 = wrow[ic];
            s += w4.x * hr[ic].x + w4.y * hr[ic].y
               + w4.z * hr[ic].z + w4.w * hr[ic].w;
        }
        acc[q] = s;
    }

    unsigned* outp = (unsigned*)(P + bw * 8192 + kap0);
    #pragma unroll
    for (int m = 0; m < 16; ++m)
        outp[m] = pack_bf2(acc[2 * m], acc[2 * m + 1]);
}

// -------------------------------------------------------------------------
// Kernel B: msg[b,v,o] += sum_{w in chunk} sum_k f[b,v,w,k] * P[b,w,k,o]
// Split-K over w-chunks of 4; LDS-tiled; fp32 accumulate; atomicAdd to msg.
__global__ __launch_bounds__(256) void msg_accum_kernel(
    const __hip_bfloat16* __restrict__ f_bf,
    const __hip_bfloat16* __restrict__ P_bf,
    float* __restrict__ msg) {
    __shared__ float fl[128][68];   // 34.8 KB, pad 68 (16B-aligned rows, conflict-free)
    __shared__ float pl[64][68];    // 17.4 KB
    int tid = threadIdx.x;
    int kc = blockIdx.x;    // 0..31 (w-chunk)
    int b  = blockIdx.y;    // 0..15
    int vg = tid >> 4;      // 0..15 ; thread's v = i*16 + vg
    int og = tid & 15;      // 0..15 ; thread's o = og*4 .. +3

    float4 acc[8];
    #pragma unroll
    for (int i = 0; i < 8; ++i) acc[i] = float4{0.f, 0.f, 0.f, 0.f};

    for (int wi = 0; wi < 4; ++wi) {
        int w = kc * 4 + wi;
        for (int kt = 0; kt < 2; ++kt) {
            // stage f tile [128 v][64 kk] (bf16 -> fp32)
            #pragma unroll
            for (int j = 0; j < 4; ++j) {
                int c = tid + 256 * j;            // 0..1023
                int v = c >> 3, p = c & 7;
                const uint4* src = (const uint4*)(f_bf +
                    ((((size_t)(b * 128 + v)) * 128 + w) * 128 + kt * 64 + p * 8));
                uint4 u = *src;
                float* dst = &fl[v][p * 8];
                dst[0] = bf_lo(u.x); dst[1] = bf_hi(u.x);
                dst[2] = bf_lo(u.y); dst[3] = bf_hi(u.y);
                dst[4] = bf_lo(u.z); dst[5] = bf_hi(u.z);
                dst[6] = bf_lo(u.w); dst[7] = bf_hi(u.w);
            }
            // stage P tile [64 kk][64 o]
            #pragma unroll
            for (int j = 0; j < 2; ++j) {
                int c = tid + 256 * j;            // 0..511
                int kk = c >> 3, o0 = (c & 7) * 8;
                const uint4* src = (const uint4*)(P_bf +
                    ((((size_t)(b * 128 + w)) * 128 + kt * 64 + kk) * 64 + o0));
                uint4 u = *src;
                float* dst = &pl[kk][o0];
                dst[0] = bf_lo(u.x); dst[1] = bf_hi(u.x);
                dst[2] = bf_lo(u.y); dst[3] = bf_hi(u.y);
                dst[4] = bf_lo(u.z); dst[5] = bf_hi(u.z);
                dst[6] = bf_lo(u.w); dst[7] = bf_hi(u.w);
            }
            __syncthreads();
            #pragma unroll 4
            for (int kk = 0; kk < 64; ++kk) {
                float4 pv = *(const float4*)&pl[kk][og * 4];
                #pragma unroll
                for (int i = 0; i < 8; ++i) {
                    float fv = fl[i * 16 + vg][kk];
                    acc[i].x += fv * pv.x;
                    acc[i].y += fv * pv.y;
                    acc[i].z += fv * pv.z;
                    acc[i].w += fv * pv.w;
                }
            }
            __syncthreads();
        }
    }
    #pragma unroll
    for (int i = 0; i < 8; ++i) {
        int v = i * 16 + vg;
        float* mp = msg + ((size_t)(b * 128 + v)) * 64 + og * 4;
        atomicAdd(mp + 0, acc[i].x);
        atomicAdd(mp + 1, acc[i].y);
        atomicAdd(mp + 2, acc[i].z);
        atomicAdd(mp + 3, acc[i].w);
    }
}

// -------------------------------------------------------------------------
// torch-style single-step GRU + mask. One block per (b,v), in-place h update.
__global__ __launch_bounds__(192) void gru_kernel(
    const float* __restrict__ msg, float* __restrict__ h,
    const float* __restrict__ Wih, const float* __restrict__ Whh,
    const float* __restrict__ bih, const float* __restrict__ bhh,
    const int* __restrict__ g_size) {
    __shared__ float m_lds[M];
    __shared__ float h_lds[H];
    __shared__ float gi[3 * H], gh[3 * H];
    int tid = threadIdx.x;
    int bv  = blockIdx.x;
    int b = bv >> 7, v = bv & 127;

    if (tid < M) m_lds[tid] = msg[bv * M + tid];
    else if (tid < M + H) h_lds[tid - M] = h[bv * H + (tid - M)];
    __syncthreads();

    {
        float si = bih[tid], sh = bhh[tid];
        const float* wi = Wih + tid * M;
        const float* wh = Whh + tid * H;
        #pragma unroll 4
        for (int k = 0; k < M; ++k) si += wi[k] * m_lds[k];
        #pragma unroll 4
        for (int k = 0; k < H; ++k) sh += wh[k] * h_lds[k];
        gi[tid] = si;
        gh[tid] = sh;
    }
    __syncthreads();
    if (tid < H) {
        float r = 1.f / (1.f + expf(-(gi[tid] + gh[tid])));
        float z = 1.f / (1.f + expf(-(gi[H + tid] + gh[H + tid])));
        float n = tanhf(gi[2 * H + tid] + r * gh[2 * H + tid]);
        float hv = (1.f - z) * n + z * h_lds[tid];
        float maskf = (v < g_size[b]) ? 1.f : 0.f;
        h[bv * H + tid] = hv * maskf;
    }
}

// -------------------------------------------------------------------------
// Readout: contrib[b,v,:] = mask * sigmoid(MLP_i([h,h_in])) * MLP_j(h)
__global__ __launch_bounds__(256) void readout_kernel(
    const float* __restrict__ h, const float* __restrict__ h_in,
    const int* __restrict__ g_size,
    const float* __restrict__ Wi0, const float* __restrict__ bi0,
    const float* __restrict__ Wi1, const float* __restrict__ bi1,
    const float* __restrict__ Wi2, const float* __restrict__ bi2,
    const float* __restrict__ Wi3, const float* __restrict__ bi3,
    const float* __restrict__ Wj0, const float* __restrict__ bj0,
    const float* __restrict__ Wj1, const float* __restrict__ bj1,
    const float* __restrict__ Wj2, const float* __restrict__ bj2,
    const float* __restrict__ Wj3, const float* __restrict__ bj3,
    float* __restrict__ contrib) {
    __shared__ float x[H + IN_];
    __shared__ float a1[128], a2[256], a3[128];
    __shared__ float gate[T];
    int tid = threadIdx.x;
    int bv  = blockIdx.x;
    int b = bv >> 7, v = bv & 127;

    if (tid < H) x[tid] = h[bv * H + tid];
    else if (tid < H + IN_) x[tid] = h_in[bv * IN_ + (tid - H)];
    __syncthreads();

    // ---- MLP_i on x[0:96]
    if (tid < 128) {
        float s = bi0[tid];
        #pragma unroll 4
        for (int c = 0; c < 96; ++c) s += x[c] * Wi0[c * 128 + tid];
        a1[tid] = fmaxf(s, 0.f);
    }
    __syncthreads();
    {
        float s = bi1[tid];
        #pragma unroll 4
        for (int k = 0; k < 128; ++k) s += a1[k] * Wi1[k * 256 + tid];
        a2[tid] = fmaxf(s, 0.f);
    }
    __syncthreads();
    if (tid < 128) {
        float s = bi2[tid];
        #pragma unroll 4
        for (int k = 0; k < 256; ++k) s += a2[k] * Wi2[k * 128 + tid];
        a3[tid] = fmaxf(s, 0.f);
    }
    __syncthreads();
    if (tid < T) {
        float s = bi3[tid];
        #pragma unroll 4
        for (int k = 0; k < 128; ++k) s += a3[k] * Wi3[k * T + tid];
        gate[tid] = 1.f / (1.f + expf(-s));
    }
    __syncthreads();

    // ---- MLP_j on x[0:64] (reuse a1,a2,a3)
    if (tid < 128) {
        float s = bj0[tid];
        #pragma unroll 4
        for (int c = 0; c < 64; ++c) s += x[c] * Wj0[c * 128 + tid];
        a1[tid] = fmaxf(s, 0.f);
    }
    __syncthreads();
    {
        float s = bj1[tid];
        #pragma unroll 4
        for (int k = 0; k < 128; ++k) s += a1[k] * Wj1[k * 256 + tid];
        a2[tid] = fmaxf(s, 0.f);
    }
    __syncthreads();
    if (tid < 128) {
        float s = bj2[tid];
        #pragma unroll 4
        for (int k = 0; k < 256; ++k) s += a2[k] * Wj2[k * 128 + tid];
        a3[tid] = fmaxf(s, 0.f);
    }
    __syncthreads();
    if (tid < T) {
        float s = bj3[tid];
        #pragma unroll 4
        for (int k = 0; k < 128; ++k) s += a3[k] * Wj3[k * T + tid];
        float maskf = (v < g_size[b]) ? 1.f : 0.f;
        contrib[bv * T + tid] = maskf * gate[tid] * s;
    }
}

// -------------------------------------------------------------------------
// res[b,:] = sum_v contrib[b,v,:]; out = log_softmax(res)
__global__ __launch_bounds__(64) void finalize_kernel(const float* __restrict__ contrib,
                                                      float* __restrict__ out) {
    __shared__ float res[T];
    int b = blockIdx.x;
    int o = threadIdx.x;
    if (o < T) {
        float s = 0.f;
        for (int v = 0; v < N; ++v) s += contrib[(b * N + v) * T + o];
        res[o] = s;
    }
    __syncthreads();
    if (o < T) {
        float mx = res[0];
        for (int i = 1; i < T; ++i) mx = fmaxf(mx, res[i]);
        float se = 0.f;
        for (int i = 0; i < T; ++i) se += expf(res[i] - mx);
        out[b * T + o] = res[o] - mx - logf(se);
    }
}

// -------------------------------------------------------------------------
extern "C" void kernel_launch(void* const* d_in, const int* in_sizes, int n_in,
                              void* d_out, int out_size, void* d_ws, size_t ws_size,
                              hipStream_t stream) {
    (void)in_sizes; (void)n_in; (void)out_size; (void)ws_size;
    const float* h_in = (const float*)d_in[0];
    const float* am   = (const float*)d_in[1];
    const int*   g_sz = (const int*)d_in[2];
    const float* We0 = (const float*)d_in[3],  *be0 = (const float*)d_in[4];
    const float* We1 = (const float*)d_in[5],  *be1 = (const float*)d_in[6];
    const float* We2 = (const float*)d_in[7],  *be2 = (const float*)d_in[8];
    const float* We3 = (const float*)d_in[9],  *be3 = (const float*)d_in[10];
    const float* Wih = (const float*)d_in[11], *Whh = (const float*)d_in[12];
    const float* bih = (const float*)d_in[13], *bhh = (const float*)d_in[14];
    const float* Wi0 = (const float*)d_in[15], *bi0 = (const float*)d_in[16];
    const float* Wj0 = (const float*)d_in[17], *bj0 = (const float*)d_in[18];
    const float* Wi1 = (const float*)d_in[19], *bi1 = (const float*)d_in[20];
    const float* Wj1 = (const float*)d_in[21], *bj1 = (const float*)d_in[22];
    const float* Wi2 = (const float*)d_in[23], *bi2 = (const float*)d_in[24];
    const float* Wj2 = (const float*)d_in[25], *bj2 = (const float*)d_in[26];
    const float* Wi3 = (const float*)d_in[27], *bi3 = (const float*)d_in[28];
    const float* Wj3 = (const float*)d_in[29], *bj3 = (const float*)d_in[30];

    // workspace layout (97.3 MB total)
    __hip_bfloat16* f_bf = (__hip_bfloat16*)d_ws;                 // 33554432 (64 MB)
    __hip_bfloat16* P_bf = f_bf + (size_t)B * N * N * K3;         // 16777216 (32 MB)
    float* h       = (float*)(P_bf + (size_t)B * N * K3 * M);     // 131072
    float* msg     = h + (size_t)B * N * H;                       // 131072
    float* contrib = msg + (size_t)B * N * M;                     // 65536
    float* out     = (float*)d_out;

    pad_h_kernel<<<(B * N * H) / 256, 256, 0, stream>>>(h_in, h);
    edge_mlp_kernel<<<(B * N * N) / 32, 256, 0, stream>>>(am, We0, be0, We1, be1,
                                                          We2, be2, f_bf);
    for (int l = 0; l < 3; ++l) {
        msg_init_kernel<<<B, 256, 0, stream>>>(h, be3, msg);
        compute_P_kernel<<<dim3(64, 32), 256, 0, stream>>>(h, We3, P_bf);
        msg_accum_kernel<<<dim3(32, 16), 256, 0, stream>>>(f_bf, P_bf, msg);
        gru_kernel<<<B * N, 192, 0, stream>>>(msg, h, Wih, Whh, bih, bhh, g_sz);
    }
    readout_kernel<<<B * N, 256, 0, stream>>>(h, h_in, g_sz,
                                              Wi0, bi0, Wi1, bi1, Wi2, bi2, Wi3, bi3,
                                              Wj0, bj0, Wj1, bj1, Wj2, bj2, Wj3, bj3,
                                              contrib);
    finalize_kernel<<<B, 64, 0, stream>>>(contrib, out);
}

// Round 5
// 473.953 us; speedup vs baseline: 4.9503x; 3.3960x over previous
//
#include <hip/hip_runtime.h>
#include <math.h>

// Problem constants
#define B   16
#define N   128
#define E   4
#define H   64
#define M   64
#define IN_ 32
#define T   32
#define K1  128
#define K2  256
#define K3  128

typedef _Float16 f16;
typedef f16  f16x8 __attribute__((ext_vector_type(8)));
typedef float f32x4 __attribute__((ext_vector_type(4)));

#define MFMA16(a, b, c) __builtin_amdgcn_mfma_f32_16x16x32_f16(a, b, c, 0, 0, 0)

// -------------------------------------------------------------------------
// h = pad(h_in) to [B,N,H], fp32 + fp16 copies
__global__ __launch_bounds__(256) void pad_h_kernel(const float* __restrict__ h_in,
                                                    float* __restrict__ h,
                                                    f16* __restrict__ h16) {
    int idx = blockIdx.x * 256 + threadIdx.x;
    if (idx >= B * N * H) return;
    int i  = idx & (H - 1);
    int bn = idx >> 6;
    float v = (i < IN_) ? h_in[bn * IN_ + i] : 0.f;
    h[idx] = v;
    h16[idx] = (f16)v;
}

// -------------------------------------------------------------------------
// Weight prep: W1t[j=256][k=128] = We1[k,j]; W2t[j=128][k=256] = We2[k,j];
// We3h = fp16(We3) (layout [k*64+o][i] already contiguous in i).
__global__ __launch_bounds__(256) void prep_weights(
    const float* __restrict__ We1, const float* __restrict__ We2,
    const float* __restrict__ We3,
    f16* __restrict__ W1t, f16* __restrict__ W2t, f16* __restrict__ We3h) {
    int idx = blockIdx.x * 256 + threadIdx.x;
    if (idx < 32768) {                       // W1t
        int j = idx >> 7, k = idx & 127;
        W1t[idx] = (f16)We1[k * 256 + j];
    } else if (idx < 65536) {                // W2t
        int t = idx - 32768;
        int j = t >> 8, k = t & 255;
        W2t[t] = (f16)We2[k * 128 + j];
    } else {                                 // We3h
        int t = idx - 65536;
        if (t < 524288) We3h[t] = (f16)We3[t];
    }
}

// -------------------------------------------------------------------------
// Edge MLP via fp16 MFMA. 64 edges per block, 256 threads (4 waves).
// layer1 (K=4) VALU fp32 -> y1 fp16 LDS; layers 2,3 MFMA; f written fp16.
__global__ __launch_bounds__(256, 2) void edge_mlp_mfma(
    const float* __restrict__ am,
    const float* __restrict__ We0, const float* __restrict__ be0,
    const f16* __restrict__ W1t, const float* __restrict__ be1,
    const f16* __restrict__ W2t, const float* __restrict__ be2,
    f16* __restrict__ f) {
    __shared__ float xl[64][4];       // 1 KB
    __shared__ f16 y1[64][136];       // 17.4 KB (pad +8 halves: 2-way only)
    __shared__ f16 y2[64][264];       // 33.8 KB
    int tid = threadIdx.x;
    int lane = tid & 63, wv = tid >> 6;
    long long g0 = (long long)blockIdx.x * 64;

    ((float*)xl)[tid] = am[g0 * 4 + tid];          // 64*4 = 256, coalesced
    __syncthreads();

    // layer 1: K=4, VALU
    {
        int j = tid & 127, e0 = (tid >> 7) * 32;
        float w0 = We0[j], w1 = We0[128 + j], w2 = We0[256 + j], w3 = We0[384 + j];
        float bb = be0[j];
        #pragma unroll 8
        for (int e = e0; e < e0 + 32; ++e) {
            float v = bb + xl[e][0] * w0 + xl[e][1] * w1
                         + xl[e][2] * w2 + xl[e][3] * w3;
            y1[e][j] = (f16)fmaxf(v, 0.f);
        }
    }
    __syncthreads();

    int m = lane & 15, q = lane >> 4;

    // layer 2: Y2[64x256] = relu(Y1[64x128] @ W1 + b1); wave owns 4 col-tiles
    {
        f32x4 acc[4][4];   // [ct][rt]
        #pragma unroll
        for (int ct = 0; ct < 4; ++ct)
            #pragma unroll
            for (int rt = 0; rt < 4; ++rt) acc[ct][rt] = (f32x4){0.f, 0.f, 0.f, 0.f};
        #pragma unroll
        for (int s = 0; s < 4; ++s) {
            int k0 = s * 32 + q * 8;
            f16x8 afr[4], bfr[4];
            #pragma unroll
            for (int rt = 0; rt < 4; ++rt)
                afr[rt] = *(const f16x8*)&y1[rt * 16 + m][k0];
            #pragma unroll
            for (int ct = 0; ct < 4; ++ct) {
                int n = (wv * 4 + ct) * 16 + m;
                bfr[ct] = *(const f16x8*)(W1t + n * 128 + k0);
            }
            #pragma unroll
            for (int ct = 0; ct < 4; ++ct)
                #pragma unroll
                for (int rt = 0; rt < 4; ++rt)
                    acc[ct][rt] = MFMA16(afr[rt], bfr[ct], acc[ct][rt]);
        }
        #pragma unroll
        for (int ct = 0; ct < 4; ++ct) {
            int n = (wv * 4 + ct) * 16 + m;
            float bb = be1[n];
            #pragma unroll
            for (int rt = 0; rt < 4; ++rt)
                #pragma unroll
                for (int r = 0; r < 4; ++r) {
                    int row = rt * 16 + q * 4 + r;
                    y2[row][n] = (f16)fmaxf(acc[ct][rt][r] + bb, 0.f);
                }
        }
    }
    __syncthreads();

    // layer 3: OUT[64x128] = relu(Y2[64x256] @ W2 + b2); wave owns 2 col-tiles
    {
        f32x4 acc[2][4];
        #pragma unroll
        for (int ct = 0; ct < 2; ++ct)
            #pragma unroll
            for (int rt = 0; rt < 4; ++rt) acc[ct][rt] = (f32x4){0.f, 0.f, 0.f, 0.f};
        #pragma unroll
        for (int s = 0; s < 8; ++s) {
            int k0 = s * 32 + q * 8;
            f16x8 afr[4], bfr[2];
            #pragma unroll
            for (int rt = 0; rt < 4; ++rt)
                afr[rt] = *(const f16x8*)&y2[rt * 16 + m][k0];
            #pragma unroll
            for (int ct = 0; ct < 2; ++ct) {
                int n = (wv * 2 + ct) * 16 + m;
                bfr[ct] = *(const f16x8*)(W2t + n * 256 + k0);
            }
            #pragma unroll
            for (int ct = 0; ct < 2; ++ct)
                #pragma unroll
                for (int rt = 0; rt < 4; ++rt)
                    acc[ct][rt] = MFMA16(afr[rt], bfr[ct], acc[ct][rt]);
        }
        #pragma unroll
        for (int ct = 0; ct < 2; ++ct) {
            int n = (wv * 2 + ct) * 16 + m;
            float bb = be2[n];
            #pragma unroll
            for (int rt = 0; rt < 4; ++rt)
                #pragma unroll
                for (int r = 0; r < 4; ++r) {
                    int row = rt * 16 + q * 4 + r;
                    y1[row][n] = (f16)fmaxf(acc[ct][rt][r] + bb, 0.f);  // reuse y1 as out-stage
                }
        }
    }
    __syncthreads();

    // coalesced copy out: f[(g0+e)*128 + k]
    #pragma unroll
    for (int j = 0; j < 4; ++j) {
        int c = tid + j * 256;          // 0..1023
        int e = c >> 4, p = c & 15;
        *(uint4*)(f + (g0 + e) * 128 + p * 8) = *(const uint4*)&y1[e][p * 8];
    }
}

// -------------------------------------------------------------------------
// msg bias: msgb[b,v,o] = sum_i be3[o*64+i] * hsum[b,i]  (same for all v)
__global__ __launch_bounds__(256) void msg_init_kernel(
    const float* __restrict__ h, const float* __restrict__ be3,
    float* __restrict__ msgb) {
    __shared__ float part[4][64];
    __shared__ float hsum[64];
    __shared__ float bias[64];
    int tid = threadIdx.x;
    int b = blockIdx.x;
    int i = tid & 63, wq = tid >> 6;
    float s = 0.f;
    for (int w = wq; w < N; w += 4) s += h[((size_t)(b * N + w)) * H + i];
    part[wq][i] = s;
    __syncthreads();
    if (tid < 64) hsum[tid] = part[0][tid] + part[1][tid] + part[2][tid] + part[3][tid];
    __syncthreads();
    if (tid < 64) {
        float sb = 0.f;
        #pragma unroll 4
        for (int ii = 0; ii < H; ++ii) sb += be3[tid * H + ii] * hsum[ii];
        bias[tid] = sb;
    }
    __syncthreads();
    for (int idx = tid; idx < N * M; idx += 256)
        msgb[(size_t)b * N * M + idx] = bias[idx & 63];
}

// -------------------------------------------------------------------------
// P GEMM: P2[(b,w), o, k] = sum_i h16[(b,w), i] * We3h[k*64+o][i]
// Grid (64 o-blocks, 16 node-tiles). C tile = 128 nodes x 128 k.
__global__ __launch_bounds__(256, 2) void p_gemm(
    const f16* __restrict__ h16, const f16* __restrict__ We3h,
    f16* __restrict__ P2) {
    __shared__ f16 Al[128][72];    // 18.4 KB (h rows)
    __shared__ f16 Bl[128][72];    // 18.4 KB (We3 rows, [k][i])
    __shared__ f16 Ol[128][136];   // 34.8 KB (out stage)
    int tid = threadIdx.x, lane = tid & 63, wv = tid >> 6;
    int ob = blockIdx.x;           // o
    int nt = blockIdx.y;           // node tile

    #pragma unroll
    for (int j = 0; j < 4; ++j) {
        int c = tid + j * 256;     // 0..1023 : stage A (128 rows x 8 uint4)
        int row = c >> 3, p = c & 7;
        *(uint4*)&Al[row][p * 8] =
            *(const uint4*)(h16 + (size_t)(nt * 128 + row) * 64 + p * 8);
    }
    #pragma unroll
    for (int j = 0; j < 4; ++j) {
        int c = tid + j * 256;     // stage B: rows k -> We3h[(k*64+ob)*64 + i]
        int k = c >> 3, p = c & 7;
        *(uint4*)&Bl[k][p * 8] =
            *(const uint4*)(We3h + ((size_t)(k * 64 + ob)) * 64 + p * 8);
    }
    __syncthreads();

    int m = lane & 15, q = lane >> 4;
    f32x4 acc[2][8];   // [ct][rt]
    #pragma unroll
    for (int ct = 0; ct < 2; ++ct)
        #pragma unroll
        for (int rt = 0; rt < 8; ++rt) acc[ct][rt] = (f32x4){0.f, 0.f, 0.f, 0.f};
    #pragma unroll
    for (int s = 0; s < 2; ++s) {
        int k0 = s * 32 + q * 8;
        f16x8 afr[8], bfr[2];
        #pragma unroll
        for (int rt = 0; rt < 8; ++rt)
            afr[rt] = *(const f16x8*)&Al[rt * 16 + m][k0];
        #pragma unroll
        for (int ct = 0; ct < 2; ++ct)
            bfr[ct] = *(const f16x8*)&Bl[(wv * 2 + ct) * 16 + m][k0];
        #pragma unroll
        for (int ct = 0; ct < 2; ++ct)
            #pragma unroll
            for (int rt = 0; rt < 8; ++rt)
                acc[ct][rt] = MFMA16(afr[rt], bfr[ct], acc[ct][rt]);
    }
    #pragma unroll
    for (int ct = 0; ct < 2; ++ct) {
        int col = (wv * 2 + ct) * 16 + m;          // k-col
        #pragma unroll
        for (int rt = 0; rt < 8; ++rt)
            #pragma unroll
            for (int r = 0; r < 4; ++r)
                Ol[rt * 16 + q * 4 + r][col] = (f16)acc[ct][rt][r];
    }
    __syncthreads();
    #pragma unroll
    for (int j = 0; j < 8; ++j) {
        int c = tid + j * 256;     // 0..2047 : 128 rows x 16 uint4
        int row = c >> 4, p = c & 15;
        *(uint4*)(P2 + ((size_t)(nt * 128 + row) * 64 + ob) * 128 + p * 8) =
            *(const uint4*)&Ol[row][p * 8];
    }
}

// -------------------------------------------------------------------------
// msg GEMM: part[ws][(b,v),o] = sum_{w in split} sum_k f[(b,v),w,k] * P2[(b,w),o,k]
// Grid (32 w-splits, 16 b). No atomics.
__global__ __launch_bounds__(256, 2) void msg_mfma(
    const f16* __restrict__ f, const f16* __restrict__ P2,
    float* __restrict__ part) {
    __shared__ f16 Al[128][136];   // 34.8 KB (f rows, one w)
    __shared__ f16 Bl[64][136];    // 17.4 KB (P2 rows [o][k])
    int tid = threadIdx.x, lane = tid & 63, wv = tid >> 6;
    int ws = blockIdx.x;
    int b  = blockIdx.y;
    int m = lane & 15, q = lane >> 4;

    f32x4 acc[2][4];   // [rt-local][ct]
    #pragma unroll
    for (int rt = 0; rt < 2; ++rt)
        #pragma unroll
        for (int ct = 0; ct < 4; ++ct) acc[rt][ct] = (f32x4){0.f, 0.f, 0.f, 0.f};

    for (int wi = 0; wi < 4; ++wi) {
        int w = ws * 4 + wi;
        #pragma unroll
        for (int j = 0; j < 8; ++j) {
            int c = tid + j * 256;   // 0..2047 : A stage 128 v x 16 uint4
            int v = c >> 4, p = c & 15;
            *(uint4*)&Al[v][p * 8] =
                *(const uint4*)(f + (((size_t)(b * 128 + v) * 128 + w) * 128) + p * 8);
        }
        #pragma unroll
        for (int j = 0; j < 4; ++j) {
            int c = tid + j * 256;   // 0..1023 : B stage 64 o rows x 16 uint4
            int o = c >> 4, p = c & 15;
            *(uint4*)&Bl[o][p * 8] =
                *(const uint4*)(P2 + (((size_t)(b * 128 + w) * 64 + o) * 128) + p * 8);
        }
        __syncthreads();
        #pragma unroll
        for (int s = 0; s < 4; ++s) {
            int k0 = s * 32 + q * 8;
            f16x8 afr[2], bfr[4];
            #pragma unroll
            for (int rt = 0; rt < 2; ++rt)
                afr[rt] = *(const f16x8*)&Al[(wv * 2 + rt) * 16 + m][k0];
            #pragma unroll
            for (int ct = 0; ct < 4; ++ct)
                bfr[ct] = *(const f16x8*)&Bl[ct * 16 + m][k0];
            #pragma unroll
            for (int rt = 0; rt < 2; ++rt)
                #pragma unroll
                for (int ct = 0; ct < 4; ++ct)
                    acc[rt][ct] = MFMA16(afr[rt], bfr[ct], acc[rt][ct]);
        }
        __syncthreads();
    }
    float* pp = part + (size_t)ws * (2048 * 64);
    #pragma unroll
    for (int rt = 0; rt < 2; ++rt)
        #pragma unroll
        for (int ct = 0; ct < 4; ++ct) {
            int o = ct * 16 + m;
            #pragma unroll
            for (int r = 0; r < 4; ++r) {
                int v = (wv * 2 + rt) * 16 + q * 4 + r;
                pp[(size_t)(b * 128 + v) * 64 + o] = acc[rt][ct][r];
            }
        }
}

// -------------------------------------------------------------------------
// GRU: msg = msgb + sum of 32 partials; torch GRU step; mask; write h + h16.
__global__ __launch_bounds__(192) void gru_kernel(
    const float* __restrict__ msgb, const float* __restrict__ part,
    float* __restrict__ h, f16* __restrict__ h16,
    const float* __restrict__ Wih, const float* __restrict__ Whh,
    const float* __restrict__ bih, const float* __restrict__ bhh,
    const int* __restrict__ g_size) {
    __shared__ float m_lds[M];
    __shared__ float h_lds[H];
    __shared__ float gi[3 * H], gh[3 * H];
    int tid = threadIdx.x;
    int bv  = blockIdx.x;
    int b = bv >> 7, v = bv & 127;

    if (tid < M) {
        float s = msgb[bv * M + tid];
        #pragma unroll 8
        for (int sp = 0; sp < 32; ++sp)
            s += part[(size_t)sp * (2048 * 64) + bv * 64 + tid];
        m_lds[tid] = s;
    } else if (tid < M + H) {
        h_lds[tid - M] = h[bv * H + (tid - M)];
    }
    __syncthreads();

    {
        float si = bih[tid], sh = bhh[tid];
        const float* wi = Wih + tid * M;
        const float* wh = Whh + tid * H;
        #pragma unroll 4
        for (int k = 0; k < M; ++k) si += wi[k] * m_lds[k];
        #pragma unroll 4
        for (int k = 0; k < H; ++k) sh += wh[k] * h_lds[k];
        gi[tid] = si;
        gh[tid] = sh;
    }
    __syncthreads();
    if (tid < H) {
        float r = 1.f / (1.f + expf(-(gi[tid] + gh[tid])));
        float z = 1.f / (1.f + expf(-(gi[H + tid] + gh[H + tid])));
        float n = tanhf(gi[2 * H + tid] + r * gh[2 * H + tid]);
        float hv = (1.f - z) * n + z * h_lds[tid];
        float maskf = (v < g_size[b]) ? 1.f : 0.f;
        hv *= maskf;
        h[bv * H + tid] = hv;
        h16[bv * H + tid] = (f16)hv;
    }
}

// -------------------------------------------------------------------------
// Readout: contrib[b,v,:] = mask * sigmoid(MLP_i([h,h_in])) * MLP_j(h)
__global__ __launch_bounds__(256) void readout_kernel(
    const float* __restrict__ h, const float* __restrict__ h_in,
    const int* __restrict__ g_size,
    const float* __restrict__ Wi0, const float* __restrict__ bi0,
    const float* __restrict__ Wi1, const float* __restrict__ bi1,
    const float* __restrict__ Wi2, const float* __restrict__ bi2,
    const float* __restrict__ Wi3, const float* __restrict__ bi3,
    const float* __restrict__ Wj0, const float* __restrict__ bj0,
    const float* __restrict__ Wj1, const float* __restrict__ bj1,
    const float* __restrict__ Wj2, const float* __restrict__ bj2,
    const float* __restrict__ Wj3, const float* __restrict__ bj3,
    float* __restrict__ contrib) {
    __shared__ float x[H + IN_];
    __shared__ float a1[128], a2[256], a3[128];
    __shared__ float gate[T];
    int tid = threadIdx.x;
    int bv  = blockIdx.x;
    int b = bv >> 7, v = bv & 127;

    if (tid < H) x[tid] = h[bv * H + tid];
    else if (tid < H + IN_) x[tid] = h_in[bv * IN_ + (tid - H)];
    __syncthreads();

    if (tid < 128) {
        float s = bi0[tid];
        #pragma unroll 4
        for (int c = 0; c < 96; ++c) s += x[c] * Wi0[c * 128 + tid];
        a1[tid] = fmaxf(s, 0.f);
    }
    __syncthreads();
    {
        float s = bi1[tid];
        #pragma unroll 4
        for (int k = 0; k < 128; ++k) s += a1[k] * Wi1[k * 256 + tid];
        a2[tid] = fmaxf(s, 0.f);
    }
    __syncthreads();
    if (tid < 128) {
        float s = bi2[tid];
        #pragma unroll 4
        for (int k = 0; k < 256; ++k) s += a2[k] * Wi2[k * 128 + tid];
        a3[tid] = fmaxf(s, 0.f);
    }
    __syncthreads();
    if (tid < T) {
        float s = bi3[tid];
        #pragma unroll 4
        for (int k = 0; k < 128; ++k) s += a3[k] * Wi3[k * T + tid];
        gate[tid] = 1.f / (1.f + expf(-s));
    }
    __syncthreads();

    if (tid < 128) {
        float s = bj0[tid];
        #pragma unroll 4
        for (int c = 0; c < 64; ++c) s += x[c] * Wj0[c * 128 + tid];
        a1[tid] = fmaxf(s, 0.f);
    }
    __syncthreads();
    {
        float s = bj1[tid];
        #pragma unroll 4
        for (int k = 0; k < 128; ++k) s += a1[k] * Wj1[k * 256 + tid];
        a2[tid] = fmaxf(s, 0.f);
    }
    __syncthreads();
    if (tid < 128) {
        float s = bj2[tid];
        #pragma unroll 4
        for (int k = 0; k < 256; ++k) s += a2[k] * Wj2[k * 128 + tid];
        a3[tid] = fmaxf(s, 0.f);
    }
    __syncthreads();
    if (tid < T) {
        float s = bj3[tid];
        #pragma unroll 4
        for (int k = 0; k < 128; ++k) s += a3[k] * Wj3[k * T + tid];
        float maskf = (v < g_size[b]) ? 1.f : 0.f;
        contrib[bv * T + tid] = maskf * gate[tid] * s;
    }
}

// -------------------------------------------------------------------------
__global__ __launch_bounds__(64) void finalize_kernel(const float* __restrict__ contrib,
                                                      float* __restrict__ out) {
    __shared__ float res[T];
    int b = blockIdx.x;
    int o = threadIdx.x;
    if (o < T) {
        float s = 0.f;
        for (int v = 0; v < N; ++v) s += contrib[(b * N + v) * T + o];
        res[o] = s;
    }
    __syncthreads();
    if (o < T) {
        float mx = res[0];
        for (int i = 1; i < T; ++i) mx = fmaxf(mx, res[i]);
        float se = 0.f;
        for (int i = 0; i < T; ++i) se += expf(res[i] - mx);
        out[b * T + o] = res[o] - mx - logf(se);
    }
}

// -------------------------------------------------------------------------
extern "C" void kernel_launch(void* const* d_in, const int* in_sizes, int n_in,
                              void* d_out, int out_size, void* d_ws, size_t ws_size,
                              hipStream_t stream) {
    (void)in_sizes; (void)n_in; (void)out_size; (void)ws_size;
    const float* h_in = (const float*)d_in[0];
    const float* am   = (const float*)d_in[1];
    const int*   g_sz = (const int*)d_in[2];
    const float* We0 = (const float*)d_in[3],  *be0 = (const float*)d_in[4];
    const float* We1 = (const float*)d_in[5],  *be1 = (const float*)d_in[6];
    const float* We2 = (const float*)d_in[7],  *be2 = (const float*)d_in[8];
    const float* We3 = (const float*)d_in[9],  *be3 = (const float*)d_in[10];
    const float* Wih = (const float*)d_in[11], *Whh = (const float*)d_in[12];
    const float* bih = (const float*)d_in[13], *bhh = (const float*)d_in[14];
    const float* Wi0 = (const float*)d_in[15], *bi0 = (const float*)d_in[16];
    const float* Wj0 = (const float*)d_in[17], *bj0 = (const float*)d_in[18];
    const float* Wi1 = (const float*)d_in[19], *bi1 = (const float*)d_in[20];
    const float* Wj1 = (const float*)d_in[21], *bj1 = (const float*)d_in[22];
    const float* Wi2 = (const float*)d_in[23], *bi2 = (const float*)d_in[24];
    const float* Wj2 = (const float*)d_in[25], *bj2 = (const float*)d_in[26];
    const float* Wi3 = (const float*)d_in[27], *bi3 = (const float*)d_in[28];
    const float* Wj3 = (const float*)d_in[29], *bj3 = (const float*)d_in[30];

    float* out = (float*)d_out;

    // workspace layout (~113.5 MB)
    f16*   f    = (f16*)d_ws;                             // 33554432 (64 MB)
    f16*   P2   = f + (size_t)33554432;                   // 16777216 (32 MB)
    float* part = (float*)(P2 + (size_t)16777216);        // 4194304  (16 MB)
    float* h    = part + (size_t)4194304;                 // 131072
    float* msgb = h + 131072;                             // 131072
    float* contrib = msgb + 131072;                       // 65536
    f16*   h16  = (f16*)(contrib + 65536);                // 131072
    f16*   W1t  = h16 + 131072;                           // 32768
    f16*   W2t  = W1t + 32768;                            // 32768
    f16*   We3h = W2t + 32768;                            // 524288

    pad_h_kernel<<<(B * N * H) / 256, 256, 0, stream>>>(h_in, h, h16);
    prep_weights<<<(65536 + 524288) / 256, 256, 0, stream>>>(We1, We2, We3,
                                                             W1t, W2t, We3h);
    edge_mlp_mfma<<<(B * N * N) / 64, 256, 0, stream>>>(am, We0, be0, W1t, be1,
                                                        W2t, be2, f);
    for (int l = 0; l < 3; ++l) {
        msg_init_kernel<<<B, 256, 0, stream>>>(h, be3, msgb);
        p_gemm<<<dim3(64, 16), 256, 0, stream>>>(h16, We3h, P2);
        msg_mfma<<<dim3(32, 16), 256, 0, stream>>>(f, P2, part);
        gru_kernel<<<B * N, 192, 0, stream>>>(msgb, part, h, h16,
                                              Wih, Whh, bih, bhh, g_sz);
    }
    readout_kernel<<<B * N, 256, 0, stream>>>(h, h_in, g_sz,
                                              Wi0, bi0, Wi1, bi1, Wi2, bi2, Wi3, bi3,
                                              Wj0, bj0, Wj1, bj1, Wj2, bj2, Wj3, bj3,
                                              contrib);
    finalize_kernel<<<B, 64, 0, stream>>>(contrib, out);
}

// Round 6
// 414.749 us; speedup vs baseline: 5.6570x; 1.1427x over previous
//
#include <hip/hip_runtime.h>
#include <math.h>

// Problem constants
#define B   16
#define N   128
#define E   4
#define H   64
#define M   64
#define IN_ 32
#define T   32
#define K1  128
#define K2  256
#define K3  128

typedef _Float16 f16;
typedef f16  f16x8 __attribute__((ext_vector_type(8)));
typedef float f32x4 __attribute__((ext_vector_type(4)));

#define MFMA16(a, b, c) __builtin_amdgcn_mfma_f32_16x16x32_f16(a, b, c, 0, 0, 0)

// fp16 weight pack offsets (halves)
#define OFF_W1T   0
#define OFF_W2T   32768
#define OFF_WE3H  65536
#define OFF_RI0   589824
#define OFF_RI1   602112
#define OFF_RI2   634880
#define OFF_RI3   667648
#define OFF_RJ0   671744
#define OFF_RJ1   679936
#define OFF_RJ2   712704
#define OFF_RJ3   745472
#define WPACK_SZ  749568

// -------------------------------------------------------------------------
// h = pad(h_in) to [B,N,H], fp32 + fp16 copies; also h_in as fp16
__global__ __launch_bounds__(256) void pad_h_kernel(const float* __restrict__ h_in,
                                                    float* __restrict__ h,
                                                    f16* __restrict__ h16,
                                                    f16* __restrict__ hin16) {
    int idx = blockIdx.x * 256 + threadIdx.x;
    if (idx >= B * N * H) return;
    int i  = idx & (H - 1);
    int bn = idx >> 6;
    float v = (i < IN_) ? h_in[bn * IN_ + i] : 0.f;
    h[idx] = v;
    h16[idx] = (f16)v;
    if (i < IN_) hin16[bn * IN_ + i] = (f16)v;
}

// -------------------------------------------------------------------------
// Weight prep into one fp16 pack:
//  W1t[j=256][k=128]=We1[k,j]; W2t[j=128][k=256]=We2[k,j]; We3h=fp16(We3);
//  readout: R*[out][in] transposed from W*[in][out].
__global__ __launch_bounds__(256) void prep_weights(
    const float* __restrict__ We1, const float* __restrict__ We2,
    const float* __restrict__ We3,
    const float* __restrict__ Wi0, const float* __restrict__ Wi1,
    const float* __restrict__ Wi2, const float* __restrict__ Wi3,
    const float* __restrict__ Wj0, const float* __restrict__ Wj1,
    const float* __restrict__ Wj2, const float* __restrict__ Wj3,
    f16* __restrict__ wp) {
    int idx = blockIdx.x * 256 + threadIdx.x;
    if (idx < OFF_W2T) {                          // W1t [256][128]
        int t = idx;
        int j = t >> 7, k = t & 127;
        wp[idx] = (f16)We1[k * 256 + j];
    } else if (idx < OFF_WE3H) {                  // W2t [128][256]
        int t = idx - OFF_W2T;
        int j = t >> 8, k = t & 255;
        wp[idx] = (f16)We2[k * 128 + j];
    } else if (idx < OFF_RI0) {                   // We3h (straight copy)
        int t = idx - OFF_WE3H;
        wp[idx] = (f16)We3[t];
    } else if (idx < OFF_RI1) {                   // Ri0 [128][96]
        int t = idx - OFF_RI0;
        int n = t / 96, c = t % 96;
        wp[idx] = (f16)Wi0[c * 128 + n];
    } else if (idx < OFF_RI2) {                   // Ri1 [256][128]
        int t = idx - OFF_RI1;
        int n = t >> 7, k = t & 127;
        wp[idx] = (f16)Wi1[k * 256 + n];
    } else if (idx < OFF_RI3) {                   // Ri2 [128][256]
        int t = idx - OFF_RI2;
        int n = t >> 8, k = t & 255;
        wp[idx] = (f16)Wi2[k * 128 + n];
    } else if (idx < OFF_RJ0) {                   // Ri3 [32][128]
        int t = idx - OFF_RI3;
        int n = t >> 7, k = t & 127;
        wp[idx] = (f16)Wi3[k * 32 + n];
    } else if (idx < OFF_RJ1) {                   // Rj0 [128][64]
        int t = idx - OFF_RJ0;
        int n = t >> 6, c = t & 63;
        wp[idx] = (f16)Wj0[c * 128 + n];
    } else if (idx < OFF_RJ2) {                   // Rj1 [256][128]
        int t = idx - OFF_RJ1;
        int n = t >> 7, k = t & 127;
        wp[idx] = (f16)Wj1[k * 256 + n];
    } else if (idx < OFF_RJ3) {                   // Rj2 [128][256]
        int t = idx - OFF_RJ2;
        int n = t >> 8, k = t & 255;
        wp[idx] = (f16)Wj2[k * 128 + n];
    } else if (idx < WPACK_SZ) {                  // Rj3 [32][128]
        int t = idx - OFF_RJ3;
        int n = t >> 7, k = t & 127;
        wp[idx] = (f16)Wj3[k * 32 + n];
    }
}

// -------------------------------------------------------------------------
// Edge MLP via fp16 MFMA. 64 edges per block, 256 threads (4 waves).
__global__ __launch_bounds__(256, 2) void edge_mlp_mfma(
    const float* __restrict__ am,
    const float* __restrict__ We0, const float* __restrict__ be0,
    const f16* __restrict__ W1t, const float* __restrict__ be1,
    const f16* __restrict__ W2t, const float* __restrict__ be2,
    f16* __restrict__ f) {
    __shared__ float xl[64][4];       // 1 KB
    __shared__ f16 y1[64][136];       // 17.4 KB
    __shared__ f16 y2[64][264];       // 33.8 KB
    int tid = threadIdx.x;
    int lane = tid & 63, wv = tid >> 6;
    long long g0 = (long long)blockIdx.x * 64;

    ((float*)xl)[tid] = am[g0 * 4 + tid];
    __syncthreads();

    // layer 1: K=4, VALU
    {
        int j = tid & 127, e0 = (tid >> 7) * 32;
        float w0 = We0[j], w1 = We0[128 + j], w2 = We0[256 + j], w3 = We0[384 + j];
        float bb = be0[j];
        #pragma unroll 8
        for (int e = e0; e < e0 + 32; ++e) {
            float v = bb + xl[e][0] * w0 + xl[e][1] * w1
                         + xl[e][2] * w2 + xl[e][3] * w3;
            y1[e][j] = (f16)fmaxf(v, 0.f);
        }
    }
    __syncthreads();

    int m = lane & 15, q = lane >> 4;

    // layer 2: Y2[64x256] = relu(Y1[64x128] @ W1 + b1)
    {
        f32x4 acc[4][4];
        #pragma unroll
        for (int ct = 0; ct < 4; ++ct)
            #pragma unroll
            for (int rt = 0; rt < 4; ++rt) acc[ct][rt] = (f32x4){0.f, 0.f, 0.f, 0.f};
        #pragma unroll
        for (int s = 0; s < 4; ++s) {
            int k0 = s * 32 + q * 8;
            f16x8 afr[4], bfr[4];
            #pragma unroll
            for (int rt = 0; rt < 4; ++rt)
                afr[rt] = *(const f16x8*)&y1[rt * 16 + m][k0];
            #pragma unroll
            for (int ct = 0; ct < 4; ++ct) {
                int n = (wv * 4 + ct) * 16 + m;
                bfr[ct] = *(const f16x8*)(W1t + n * 128 + k0);
            }
            #pragma unroll
            for (int ct = 0; ct < 4; ++ct)
                #pragma unroll
                for (int rt = 0; rt < 4; ++rt)
                    acc[ct][rt] = MFMA16(afr[rt], bfr[ct], acc[ct][rt]);
        }
        #pragma unroll
        for (int ct = 0; ct < 4; ++ct) {
            int n = (wv * 4 + ct) * 16 + m;
            float bb = be1[n];
            #pragma unroll
            for (int rt = 0; rt < 4; ++rt)
                #pragma unroll
                for (int r = 0; r < 4; ++r) {
                    int row = rt * 16 + q * 4 + r;
                    y2[row][n] = (f16)fmaxf(acc[ct][rt][r] + bb, 0.f);
                }
        }
    }
    __syncthreads();

    // layer 3: OUT[64x128] = relu(Y2[64x256] @ W2 + b2)
    {
        f32x4 acc[2][4];
        #pragma unroll
        for (int ct = 0; ct < 2; ++ct)
            #pragma unroll
            for (int rt = 0; rt < 4; ++rt) acc[ct][rt] = (f32x4){0.f, 0.f, 0.f, 0.f};
        #pragma unroll
        for (int s = 0; s < 8; ++s) {
            int k0 = s * 32 + q * 8;
            f16x8 afr[4], bfr[2];
            #pragma unroll
            for (int rt = 0; rt < 4; ++rt)
                afr[rt] = *(const f16x8*)&y2[rt * 16 + m][k0];
            #pragma unroll
            for (int ct = 0; ct < 2; ++ct) {
                int n = (wv * 2 + ct) * 16 + m;
                bfr[ct] = *(const f16x8*)(W2t + n * 256 + k0);
            }
            #pragma unroll
            for (int ct = 0; ct < 2; ++ct)
                #pragma unroll
                for (int rt = 0; rt < 4; ++rt)
                    acc[ct][rt] = MFMA16(afr[rt], bfr[ct], acc[ct][rt]);
        }
        #pragma unroll
        for (int ct = 0; ct < 2; ++ct) {
            int n = (wv * 2 + ct) * 16 + m;
            float bb = be2[n];
            #pragma unroll
            for (int rt = 0; rt < 4; ++rt)
                #pragma unroll
                for (int r = 0; r < 4; ++r) {
                    int row = rt * 16 + q * 4 + r;
                    y1[row][n] = (f16)fmaxf(acc[ct][rt][r] + bb, 0.f);
                }
        }
    }
    __syncthreads();

    #pragma unroll
    for (int j = 0; j < 4; ++j) {
        int c = tid + j * 256;
        int e = c >> 4, p = c & 15;
        *(uint4*)(f + (g0 + e) * 128 + p * 8) = *(const uint4*)&y1[e][p * 8];
    }
}

// -------------------------------------------------------------------------
// msg bias: msgb[b,v,o] = sum_i be3[o*64+i] * hsum[b,i]
__global__ __launch_bounds__(256) void msg_init_kernel(
    const float* __restrict__ h, const float* __restrict__ be3,
    float* __restrict__ msgb) {
    __shared__ float part[4][64];
    __shared__ float hsum[64];
    __shared__ float bias[64];
    int tid = threadIdx.x;
    int b = blockIdx.x;
    int i = tid & 63, wq = tid >> 6;
    float s = 0.f;
    for (int w = wq; w < N; w += 4) s += h[((size_t)(b * N + w)) * H + i];
    part[wq][i] = s;
    __syncthreads();
    if (tid < 64) hsum[tid] = part[0][tid] + part[1][tid] + part[2][tid] + part[3][tid];
    __syncthreads();
    if (tid < 64) {
        float sb = 0.f;
        #pragma unroll 4
        for (int ii = 0; ii < H; ++ii) sb += be3[tid * H + ii] * hsum[ii];
        bias[tid] = sb;
    }
    __syncthreads();
    for (int idx = tid; idx < N * M; idx += 256)
        msgb[(size_t)b * N * M + idx] = bias[idx & 63];
}

// -------------------------------------------------------------------------
// P GEMM: P2[(b,w), o, k] = sum_i h16[(b,w), i] * We3h[k*64+o][i]
__global__ __launch_bounds__(256, 2) void p_gemm(
    const f16* __restrict__ h16, const f16* __restrict__ We3h,
    f16* __restrict__ P2) {
    __shared__ f16 Al[128][72];
    __shared__ f16 Bl[128][72];
    __shared__ f16 Ol[128][136];
    int tid = threadIdx.x, lane = tid & 63, wv = tid >> 6;
    int ob = blockIdx.x;
    int nt = blockIdx.y;

    #pragma unroll
    for (int j = 0; j < 4; ++j) {
        int c = tid + j * 256;
        int row = c >> 3, p = c & 7;
        *(uint4*)&Al[row][p * 8] =
            *(const uint4*)(h16 + (size_t)(nt * 128 + row) * 64 + p * 8);
    }
    #pragma unroll
    for (int j = 0; j < 4; ++j) {
        int c = tid + j * 256;
        int k = c >> 3, p = c & 7;
        *(uint4*)&Bl[k][p * 8] =
            *(const uint4*)(We3h + ((size_t)(k * 64 + ob)) * 64 + p * 8);
    }
    __syncthreads();

    int m = lane & 15, q = lane >> 4;
    f32x4 acc[2][8];
    #pragma unroll
    for (int ct = 0; ct < 2; ++ct)
        #pragma unroll
        for (int rt = 0; rt < 8; ++rt) acc[ct][rt] = (f32x4){0.f, 0.f, 0.f, 0.f};
    #pragma unroll
    for (int s = 0; s < 2; ++s) {
        int k0 = s * 32 + q * 8;
        f16x8 afr[8], bfr[2];
        #pragma unroll
        for (int rt = 0; rt < 8; ++rt)
            afr[rt] = *(const f16x8*)&Al[rt * 16 + m][k0];
        #pragma unroll
        for (int ct = 0; ct < 2; ++ct)
            bfr[ct] = *(const f16x8*)&Bl[(wv * 2 + ct) * 16 + m][k0];
        #pragma unroll
        for (int ct = 0; ct < 2; ++ct)
            #pragma unroll
            for (int rt = 0; rt < 8; ++rt)
                acc[ct][rt] = MFMA16(afr[rt], bfr[ct], acc[ct][rt]);
    }
    #pragma unroll
    for (int ct = 0; ct < 2; ++ct) {
        int col = (wv * 2 + ct) * 16 + m;
        #pragma unroll
        for (int rt = 0; rt < 8; ++rt)
            #pragma unroll
            for (int r = 0; r < 4; ++r)
                Ol[rt * 16 + q * 4 + r][col] = (f16)acc[ct][rt][r];
    }
    __syncthreads();
    #pragma unroll
    for (int j = 0; j < 8; ++j) {
        int c = tid + j * 256;
        int row = c >> 4, p = c & 15;
        *(uint4*)(P2 + ((size_t)(nt * 128 + row) * 64 + ob) * 128 + p * 8) =
            *(const uint4*)&Ol[row][p * 8];
    }
}

// -------------------------------------------------------------------------
// msg GEMM: part[ws][(b,v),o] = sum_{w in split} sum_k f[(b,v),w,k]*P2[(b,w),o,k]
__global__ __launch_bounds__(256, 2) void msg_mfma(
    const f16* __restrict__ f, const f16* __restrict__ P2,
    float* __restrict__ part) {
    __shared__ f16 Al[128][136];
    __shared__ f16 Bl[64][136];
    int tid = threadIdx.x, lane = tid & 63, wv = tid >> 6;
    int ws = blockIdx.x;
    int b  = blockIdx.y;
    int m = lane & 15, q = lane >> 4;

    f32x4 acc[2][4];
    #pragma unroll
    for (int rt = 0; rt < 2; ++rt)
        #pragma unroll
        for (int ct = 0; ct < 4; ++ct) acc[rt][ct] = (f32x4){0.f, 0.f, 0.f, 0.f};

    for (int wi = 0; wi < 4; ++wi) {
        int w = ws * 4 + wi;
        #pragma unroll
        for (int j = 0; j < 8; ++j) {
            int c = tid + j * 256;
            int v = c >> 4, p = c & 15;
            *(uint4*)&Al[v][p * 8] =
                *(const uint4*)(f + (((size_t)(b * 128 + v) * 128 + w) * 128) + p * 8);
        }
        #pragma unroll
        for (int j = 0; j < 4; ++j) {
            int c = tid + j * 256;
            int o = c >> 4, p = c & 15;
            *(uint4*)&Bl[o][p * 8] =
                *(const uint4*)(P2 + (((size_t)(b * 128 + w) * 64 + o) * 128) + p * 8);
        }
        __syncthreads();
        #pragma unroll
        for (int s = 0; s < 4; ++s) {
            int k0 = s * 32 + q * 8;
            f16x8 afr[2], bfr[4];
            #pragma unroll
            for (int rt = 0; rt < 2; ++rt)
                afr[rt] = *(const f16x8*)&Al[(wv * 2 + rt) * 16 + m][k0];
            #pragma unroll
            for (int ct = 0; ct < 4; ++ct)
                bfr[ct] = *(const f16x8*)&Bl[ct * 16 + m][k0];
            #pragma unroll
            for (int rt = 0; rt < 2; ++rt)
                #pragma unroll
                for (int ct = 0; ct < 4; ++ct)
                    acc[rt][ct] = MFMA16(afr[rt], bfr[ct], acc[rt][ct]);
        }
        __syncthreads();
    }
    float* pp = part + (size_t)ws * (2048 * 64);
    #pragma unroll
    for (int rt = 0; rt < 2; ++rt)
        #pragma unroll
        for (int ct = 0; ct < 4; ++ct) {
            int o = ct * 16 + m;
            #pragma unroll
            for (int r = 0; r < 4; ++r) {
                int v = (wv * 2 + rt) * 16 + q * 4 + r;
                pp[(size_t)(b * 128 + v) * 64 + o] = acc[rt][ct][r];
            }
        }
}

// -------------------------------------------------------------------------
// GRU: msg = msgb + sum of 32 partials; torch GRU step; mask; write h + h16.
__global__ __launch_bounds__(192) void gru_kernel(
    const float* __restrict__ msgb, const float* __restrict__ part,
    float* __restrict__ h, f16* __restrict__ h16,
    const float* __restrict__ Wih, const float* __restrict__ Whh,
    const float* __restrict__ bih, const float* __restrict__ bhh,
    const int* __restrict__ g_size) {
    __shared__ float m_lds[M];
    __shared__ float h_lds[H];
    __shared__ float gi[3 * H], gh[3 * H];
    int tid = threadIdx.x;
    int bv  = blockIdx.x;
    int b = bv >> 7, v = bv & 127;

    if (tid < M) {
        float s = msgb[bv * M + tid];
        #pragma unroll 8
        for (int sp = 0; sp < 32; ++sp)
            s += part[(size_t)sp * (2048 * 64) + bv * 64 + tid];
        m_lds[tid] = s;
    } else if (tid < M + H) {
        h_lds[tid - M] = h[bv * H + (tid - M)];
    }
    __syncthreads();

    {
        float si = bih[tid], sh = bhh[tid];
        const float* wi = Wih + tid * M;
        const float* wh = Whh + tid * H;
        #pragma unroll 4
        for (int k = 0; k < M; ++k) si += wi[k] * m_lds[k];
        #pragma unroll 4
        for (int k = 0; k < H; ++k) sh += wh[k] * h_lds[k];
        gi[tid] = si;
        gh[tid] = sh;
    }
    __syncthreads();
    if (tid < H) {
        float r = 1.f / (1.f + expf(-(gi[tid] + gh[tid])));
        float z = 1.f / (1.f + expf(-(gi[H + tid] + gh[H + tid])));
        float n = tanhf(gi[2 * H + tid] + r * gh[2 * H + tid]);
        float hv = (1.f - z) * n + z * h_lds[tid];
        float maskf = (v < g_size[b]) ? 1.f : 0.f;
        hv *= maskf;
        h[bv * H + tid] = hv;
        h16[bv * H + tid] = (f16)hv;
    }
}

// -------------------------------------------------------------------------
// Readout via MFMA: 64 blocks x 32 nodes. i-chain -> gate (LDS), j-chain ->
// val, fused mask*gate*val store to contrib.
__global__ __launch_bounds__(256, 4) void readout_mfma(
    const f16* __restrict__ h16, const f16* __restrict__ hin16,
    const int* __restrict__ g_size,
    const f16* __restrict__ Ri0, const float* __restrict__ bi0,
    const f16* __restrict__ Ri1, const float* __restrict__ bi1,
    const f16* __restrict__ Ri2, const float* __restrict__ bi2,
    const f16* __restrict__ Ri3, const float* __restrict__ bi3,
    const f16* __restrict__ Rj0, const float* __restrict__ bj0,
    const f16* __restrict__ Rj1, const float* __restrict__ bj1,
    const f16* __restrict__ Rj2, const float* __restrict__ bj2,
    const f16* __restrict__ Rj3, const float* __restrict__ bj3,
    float* __restrict__ contrib) {
    __shared__ f16 Xl[32][104];    // [h16(64) | hin16(32)] per node
    __shared__ f16 A1[32][136];
    __shared__ f16 A2[32][264];
    __shared__ float Gl[32][36];   // gate
    int tid = threadIdx.x, lane = tid & 63, wv = tid >> 6;
    int m = lane & 15, q = lane >> 4;
    int r0 = blockIdx.x * 32;      // first node row

    {   // stage X
        int row = tid >> 3, p = tid & 7;
        *(uint4*)&Xl[row][p * 8] = *(const uint4*)(h16 + (size_t)(r0 + row) * 64 + p * 8);
        if (tid < 128) {
            int row2 = tid >> 2, p2 = tid & 3;
            *(uint4*)&Xl[row2][64 + p2 * 8] =
                *(const uint4*)(hin16 + (size_t)(r0 + row2) * 32 + p2 * 8);
        }
    }
    __syncthreads();

    // ---- i-chain L0: [32x96]@Ri0 -> A1[32x128]
    {
        f32x4 acc[2][2];
        #pragma unroll
        for (int ct = 0; ct < 2; ++ct)
            #pragma unroll
            for (int rt = 0; rt < 2; ++rt) acc[ct][rt] = (f32x4){0.f, 0.f, 0.f, 0.f};
        #pragma unroll
        for (int s = 0; s < 3; ++s) {
            int k0 = s * 32 + q * 8;
            f16x8 afr[2], bfr[2];
            #pragma unroll
            for (int rt = 0; rt < 2; ++rt) afr[rt] = *(const f16x8*)&Xl[rt * 16 + m][k0];
            #pragma unroll
            for (int ct = 0; ct < 2; ++ct)
                bfr[ct] = *(const f16x8*)(Ri0 + ((wv * 2 + ct) * 16 + m) * 96 + k0);
            #pragma unroll
            for (int ct = 0; ct < 2; ++ct)
                #pragma unroll
                for (int rt = 0; rt < 2; ++rt)
                    acc[ct][rt] = MFMA16(afr[rt], bfr[ct], acc[ct][rt]);
        }
        #pragma unroll
        for (int ct = 0; ct < 2; ++ct) {
            int n = (wv * 2 + ct) * 16 + m;
            float bb = bi0[n];
            #pragma unroll
            for (int rt = 0; rt < 2; ++rt)
                #pragma unroll
                for (int r = 0; r < 4; ++r)
                    A1[rt * 16 + q * 4 + r][n] = (f16)fmaxf(acc[ct][rt][r] + bb, 0.f);
        }
    }
    __syncthreads();

    // ---- i-chain L1: A1[32x128]@Ri1 -> A2[32x256]
    {
        f32x4 acc[4][2];
        #pragma unroll
        for (int ct = 0; ct < 4; ++ct)
            #pragma unroll
            for (int rt = 0; rt < 2; ++rt) acc[ct][rt] = (f32x4){0.f, 0.f, 0.f, 0.f};
        #pragma unroll
        for (int s = 0; s < 4; ++s) {
            int k0 = s * 32 + q * 8;
            f16x8 afr[2], bfr[4];
            #pragma unroll
            for (int rt = 0; rt < 2; ++rt) afr[rt] = *(const f16x8*)&A1[rt * 16 + m][k0];
            #pragma unroll
            for (int ct = 0; ct < 4; ++ct)
                bfr[ct] = *(const f16x8*)(Ri1 + ((wv * 4 + ct) * 16 + m) * 128 + k0);
            #pragma unroll
            for (int ct = 0; ct < 4; ++ct)
                #pragma unroll
                for (int rt = 0; rt < 2; ++rt)
                    acc[ct][rt] = MFMA16(afr[rt], bfr[ct], acc[ct][rt]);
        }
        #pragma unroll
        for (int ct = 0; ct < 4; ++ct) {
            int n = (wv * 4 + ct) * 16 + m;
            float bb = bi1[n];
            #pragma unroll
            for (int rt = 0; rt < 2; ++rt)
                #pragma unroll
                for (int r = 0; r < 4; ++r)
                    A2[rt * 16 + q * 4 + r][n] = (f16)fmaxf(acc[ct][rt][r] + bb, 0.f);
        }
    }
    __syncthreads();

    // ---- i-chain L2: A2[32x256]@Ri2 -> A1[32x128]
    {
        f32x4 acc[2][2];
        #pragma unroll
        for (int ct = 0; ct < 2; ++ct)
            #pragma unroll
            for (int rt = 0; rt < 2; ++rt) acc[ct][rt] = (f32x4){0.f, 0.f, 0.f, 0.f};
        #pragma unroll
        for (int s = 0; s < 8; ++s) {
            int k0 = s * 32 + q * 8;
            f16x8 afr[2], bfr[2];
            #pragma unroll
            for (int rt = 0; rt < 2; ++rt) afr[rt] = *(const f16x8*)&A2[rt * 16 + m][k0];
            #pragma unroll
            for (int ct = 0; ct < 2; ++ct)
                bfr[ct] = *(const f16x8*)(Ri2 + ((wv * 2 + ct) * 16 + m) * 256 + k0);
            #pragma unroll
            for (int ct = 0; ct < 2; ++ct)
                #pragma unroll
                for (int rt = 0; rt < 2; ++rt)
                    acc[ct][rt] = MFMA16(afr[rt], bfr[ct], acc[ct][rt]);
        }
        __syncthreads();   // A1 about to be overwritten; L1 readers done anyway
        #pragma unroll
        for (int ct = 0; ct < 2; ++ct) {
            int n = (wv * 2 + ct) * 16 + m;
            float bb = bi2[n];
            #pragma unroll
            for (int rt = 0; rt < 2; ++rt)
                #pragma unroll
                for (int r = 0; r < 4; ++r)
                    A1[rt * 16 + q * 4 + r][n] = (f16)fmaxf(acc[ct][rt][r] + bb, 0.f);
        }
    }
    __syncthreads();

    // ---- i-chain L3: A1[32x128]@Ri3 -> gate[32x32] (waves 0,1)
    if (wv < 2) {
        f32x4 acc[2];
        acc[0] = (f32x4){0.f, 0.f, 0.f, 0.f};
        acc[1] = (f32x4){0.f, 0.f, 0.f, 0.f};
        int n = wv * 16 + m;
        #pragma unroll
        for (int s = 0; s < 4; ++s) {
            int k0 = s * 32 + q * 8;
            f16x8 bfr = *(const f16x8*)(Ri3 + n * 128 + k0);
            #pragma unroll
            for (int rt = 0; rt < 2; ++rt) {
                f16x8 afr = *(const f16x8*)&A1[rt * 16 + m][k0];
                acc[rt] = MFMA16(afr, bfr, acc[rt]);
            }
        }
        float bb = bi3[n];
        #pragma unroll
        for (int rt = 0; rt < 2; ++rt)
            #pragma unroll
            for (int r = 0; r < 4; ++r)
                Gl[rt * 16 + q * 4 + r][n] = 1.f / (1.f + expf(-(acc[rt][r] + bb)));
    }
    __syncthreads();

    // ---- j-chain L0: Xl[:, :64]@Rj0 -> A1[32x128]
    {
        f32x4 acc[2][2];
        #pragma unroll
        for (int ct = 0; ct < 2; ++ct)
            #pragma unroll
            for (int rt = 0; rt < 2; ++rt) acc[ct][rt] = (f32x4){0.f, 0.f, 0.f, 0.f};
        #pragma unroll
        for (int s = 0; s < 2; ++s) {
            int k0 = s * 32 + q * 8;
            f16x8 afr[2], bfr[2];
            #pragma unroll
            for (int rt = 0; rt < 2; ++rt) afr[rt] = *(const f16x8*)&Xl[rt * 16 + m][k0];
            #pragma unroll
            for (int ct = 0; ct < 2; ++ct)
                bfr[ct] = *(const f16x8*)(Rj0 + ((wv * 2 + ct) * 16 + m) * 64 + k0);
            #pragma unroll
            for (int ct = 0; ct < 2; ++ct)
                #pragma unroll
                for (int rt = 0; rt < 2; ++rt)
                    acc[ct][rt] = MFMA16(afr[rt], bfr[ct], acc[ct][rt]);
        }
        __syncthreads();   // L3 readers of A1 done
        #pragma unroll
        for (int ct = 0; ct < 2; ++ct) {
            int n = (wv * 2 + ct) * 16 + m;
            float bb = bj0[n];
            #pragma unroll
            for (int rt = 0; rt < 2; ++rt)
                #pragma unroll
                for (int r = 0; r < 4; ++r)
                    A1[rt * 16 + q * 4 + r][n] = (f16)fmaxf(acc[ct][rt][r] + bb, 0.f);
        }
    }
    __syncthreads();

    // ---- j-chain L1: A1@Rj1 -> A2[32x256]
    {
        f32x4 acc[4][2];
        #pragma unroll
        for (int ct = 0; ct < 4; ++ct)
            #pragma unroll
            for (int rt = 0; rt < 2; ++rt) acc[ct][rt] = (f32x4){0.f, 0.f, 0.f, 0.f};
        #pragma unroll
        for (int s = 0; s < 4; ++s) {
            int k0 = s * 32 + q * 8;
            f16x8 afr[2], bfr[4];
            #pragma unroll
            for (int rt = 0; rt < 2; ++rt) afr[rt] = *(const f16x8*)&A1[rt * 16 + m][k0];
            #pragma unroll
            for (int ct = 0; ct < 4; ++ct)
                bfr[ct] = *(const f16x8*)(Rj1 + ((wv * 4 + ct) * 16 + m) * 128 + k0);
            #pragma unroll
            for (int ct = 0; ct < 4; ++ct)
                #pragma unroll
                for (int rt = 0; rt < 2; ++rt)
                    acc[ct][rt] = MFMA16(afr[rt], bfr[ct], acc[ct][rt]);
        }
        #pragma unroll
        for (int ct = 0; ct < 4; ++ct) {
            int n = (wv * 4 + ct) * 16 + m;
            float bb = bj1[n];
            #pragma unroll
            for (int rt = 0; rt < 2; ++rt)
                #pragma unroll
                for (int r = 0; r < 4; ++r)
                    A2[rt * 16 + q * 4 + r][n] = (f16)fmaxf(acc[ct][rt][r] + bb, 0.f);
        }
    }
    __syncthreads();

    // ---- j-chain L2: A2@Rj2 -> A1[32x128]
    {
        f32x4 acc[2][2];
        #pragma unroll
        for (int ct = 0; ct < 2; ++ct)
            #pragma unroll
            for (int rt = 0; rt < 2; ++rt) acc[ct][rt] = (f32x4){0.f, 0.f, 0.f, 0.f};
        #pragma unroll
        for (int s = 0; s < 8; ++s) {
            int k0 = s * 32 + q * 8;
            f16x8 afr[2], bfr[2];
            #pragma unroll
            for (int rt = 0; rt < 2; ++rt) afr[rt] = *(const f16x8*)&A2[rt * 16 + m][k0];
            #pragma unroll
            for (int ct = 0; ct < 2; ++ct)
                bfr[ct] = *(const f16x8*)(Rj2 + ((wv * 2 + ct) * 16 + m) * 256 + k0);
            #pragma unroll
            for (int ct = 0; ct < 2; ++ct)
                #pragma unroll
                for (int rt = 0; rt < 2; ++rt)
                    acc[ct][rt] = MFMA16(afr[rt], bfr[ct], acc[ct][rt]);
        }
        __syncthreads();
        #pragma unroll
        for (int ct = 0; ct < 2; ++ct) {
            int n = (wv * 2 + ct) * 16 + m;
            float bb = bj2[n];
            #pragma unroll
            for (int rt = 0; rt < 2; ++rt)
                #pragma unroll
                for (int r = 0; r < 4; ++r)
                    A1[rt * 16 + q * 4 + r][n] = (f16)fmaxf(acc[ct][rt][r] + bb, 0.f);
        }
    }
    __syncthreads();

    // ---- j-chain L3 + combine: val; contrib = mask*gate*val
    if (wv < 2) {
        f32x4 acc[2];
        acc[0] = (f32x4){0.f, 0.f, 0.f, 0.f};
        acc[1] = (f32x4){0.f, 0.f, 0.f, 0.f};
        int n = wv * 16 + m;
        #pragma unroll
        for (int s = 0; s < 4; ++s) {
            int k0 = s * 32 + q * 8;
            f16x8 bfr = *(const f16x8*)(Rj3 + n * 128 + k0);
            #pragma unroll
            for (int rt = 0; rt < 2; ++rt) {
                f16x8 afr = *(const f16x8*)&A1[rt * 16 + m][k0];
                acc[rt] = MFMA16(afr, bfr, acc[rt]);
            }
        }
        float bb = bj3[n];
        #pragma unroll
        for (int rt = 0; rt < 2; ++rt)
            #pragma unroll
            for (int r = 0; r < 4; ++r) {
                int row = rt * 16 + q * 4 + r;
                int rg = r0 + row;
                int b = rg >> 7, v = rg & 127;
                float maskf = (v < g_size[b]) ? 1.f : 0.f;
                contrib[(size_t)rg * T + n] = maskf * Gl[row][n] * (acc[rt][r] + bb);
            }
    }
}

// -------------------------------------------------------------------------
__global__ __launch_bounds__(64) void finalize_kernel(const float* __restrict__ contrib,
                                                      float* __restrict__ out) {
    __shared__ float res[T];
    int b = blockIdx.x;
    int o = threadIdx.x;
    if (o < T) {
        float s = 0.f;
        for (int v = 0; v < N; ++v) s += contrib[(b * N + v) * T + o];
        res[o] = s;
    }
    __syncthreads();
    if (o < T) {
        float mx = res[0];
        for (int i = 1; i < T; ++i) mx = fmaxf(mx, res[i]);
        float se = 0.f;
        for (int i = 0; i < T; ++i) se += expf(res[i] - mx);
        out[b * T + o] = res[o] - mx - logf(se);
    }
}

// -------------------------------------------------------------------------
extern "C" void kernel_launch(void* const* d_in, const int* in_sizes, int n_in,
                              void* d_out, int out_size, void* d_ws, size_t ws_size,
                              hipStream_t stream) {
    (void)in_sizes; (void)n_in; (void)out_size; (void)ws_size;
    const float* h_in = (const float*)d_in[0];
    const float* am   = (const float*)d_in[1];
    const int*   g_sz = (const int*)d_in[2];
    const float* We0 = (const float*)d_in[3],  *be0 = (const float*)d_in[4];
    const float* We1 = (const float*)d_in[5],  *be1 = (const float*)d_in[6];
    const float* We2 = (const float*)d_in[7],  *be2 = (const float*)d_in[8];
    const float* We3 = (const float*)d_in[9],  *be3 = (const float*)d_in[10];
    const float* Wih = (const float*)d_in[11], *Whh = (const float*)d_in[12];
    const float* bih = (const float*)d_in[13], *bhh = (const float*)d_in[14];
    const float* Wi0 = (const float*)d_in[15], *bi0 = (const float*)d_in[16];
    const float* Wj0 = (const float*)d_in[17], *bj0 = (const float*)d_in[18];
    const float* Wi1 = (const float*)d_in[19], *bi1 = (const float*)d_in[20];
    const float* Wj1 = (const float*)d_in[21], *bj1 = (const float*)d_in[22];
    const float* Wi2 = (const float*)d_in[23], *bi2 = (const float*)d_in[24];
    const float* Wj2 = (const float*)d_in[25], *bj2 = (const float*)d_in[26];
    const float* Wi3 = (const float*)d_in[27], *bi3 = (const float*)d_in[28];
    const float* Wj3 = (const float*)d_in[29], *bj3 = (const float*)d_in[30];

    float* out = (float*)d_out;

    // workspace layout (~115 MB)
    f16*   f    = (f16*)d_ws;                             // 33554432 halves
    f16*   P2   = f + (size_t)33554432;                   // 16777216 halves
    float* part = (float*)(P2 + (size_t)16777216);        // 4194304 floats
    float* h    = part + (size_t)4194304;                 // 131072
    float* msgb = h + 131072;                             // 131072
    float* contrib = msgb + 131072;                       // 65536
    f16*   h16  = (f16*)(contrib + 65536);                // 131072 halves
    f16*   hin16 = h16 + 131072;                          // 65536 halves
    f16*   wp   = hin16 + 65536;                          // 749568 halves

    f16* W1t  = wp + OFF_W1T;
    f16* W2t  = wp + OFF_W2T;
    f16* We3h = wp + OFF_WE3H;
    f16* Ri0  = wp + OFF_RI0;
    f16* Ri1  = wp + OFF_RI1;
    f16* Ri2  = wp + OFF_RI2;
    f16* Ri3  = wp + OFF_RI3;
    f16* Rj0  = wp + OFF_RJ0;
    f16* Rj1  = wp + OFF_RJ1;
    f16* Rj2  = wp + OFF_RJ2;
    f16* Rj3  = wp + OFF_RJ3;

    pad_h_kernel<<<(B * N * H) / 256, 256, 0, stream>>>(h_in, h, h16, hin16);
    prep_weights<<<WPACK_SZ / 256, 256, 0, stream>>>(We1, We2, We3,
                                                     Wi0, Wi1, Wi2, Wi3,
                                                     Wj0, Wj1, Wj2, Wj3, wp);
    edge_mlp_mfma<<<(B * N * N) / 64, 256, 0, stream>>>(am, We0, be0, W1t, be1,
                                                        W2t, be2, f);
    for (int l = 0; l < 3; ++l) {
        msg_init_kernel<<<B, 256, 0, stream>>>(h, be3, msgb);
        p_gemm<<<dim3(64, 16), 256, 0, stream>>>(h16, We3h, P2);
        msg_mfma<<<dim3(32, 16), 256, 0, stream>>>(f, P2, part);
        gru_kernel<<<B * N, 192, 0, stream>>>(msgb, part, h, h16,
                                              Wih, Whh, bih, bhh, g_sz);
    }
    readout_mfma<<<64, 256, 0, stream>>>(h16, hin16, g_sz,
                                         Ri0, bi0, Ri1, bi1, Ri2, bi2, Ri3, bi3,
                                         Rj0, bj0, Rj1, bj1, Rj2, bj2, Rj3, bj3,
                                         contrib);
    finalize_kernel<<<B, 64, 0, stream>>>(contrib, out);
}

// Round 9
// 412.143 us; speedup vs baseline: 5.6927x; 1.0063x over previous
//
#include <hip/hip_runtime.h>
#include <math.h>

// Problem constants
#define B   16
#define N   128
#define E   4
#define H   64
#define M   64
#define IN_ 32
#define T   32
#define K1  128
#define K2  256
#define K3  128

typedef _Float16 f16;
typedef f16  f16x8 __attribute__((ext_vector_type(8)));
typedef float f32x4 __attribute__((ext_vector_type(4)));

#define MFMA16(a, b, c) __builtin_amdgcn_mfma_f32_16x16x32_f16(a, b, c, 0, 0, 0)

// fp16 weight pack offsets (halves)
#define OFF_W1T   0
#define OFF_W2T   32768
#define OFF_WE3H  65536
#define OFF_RI0   589824
#define OFF_RI1   602112
#define OFF_RI2   634880
#define OFF_RI3   667648
#define OFF_RJ0   671744
#define OFF_RJ1   679936
#define OFF_RJ2   712704
#define OFF_RJ3   745472
#define WPACK_SZ  749568

// Shared-memory union for multi-task kernels: R6-proven 2-D arrays, unchanged
// indexing. sizeof = 71680 B (pg branch) -> 2 blocks/CU.
union SmemU {
    struct { float xl[64][4]; f16 y1[64][136]; f16 y2[64][264]; } e;   // 52224
    struct { f16 Al[128][72]; f16 Bl[128][72]; f16 Ol[128][136]; } pg; // 71680
    struct { float prt[4][64]; float hsum[64]; float bias[64]; } bi;   // 1536
};

// -------------------------------------------------------------------------
// prep: pad h (fp32/fp16 + hin16) AND build fp16 weight pack. One launch.
__global__ __launch_bounds__(256) void prep_kernel(
    const float* __restrict__ h_in,
    const float* __restrict__ We1, const float* __restrict__ We2,
    const float* __restrict__ We3,
    const float* __restrict__ Wi0, const float* __restrict__ Wi1,
    const float* __restrict__ Wi2, const float* __restrict__ Wi3,
    const float* __restrict__ Wj0, const float* __restrict__ Wj1,
    const float* __restrict__ Wj2, const float* __restrict__ Wj3,
    float* __restrict__ h, f16* __restrict__ h16, f16* __restrict__ hin16,
    f16* __restrict__ wp) {
    int idx = blockIdx.x * 256 + threadIdx.x;
    if (idx < B * N * H) {
        int i  = idx & (H - 1);
        int bn = idx >> 6;
        float v = (i < IN_) ? h_in[bn * IN_ + i] : 0.f;
        h[idx] = v;
        h16[idx] = (f16)v;
        if (i < IN_) hin16[bn * IN_ + i] = (f16)v;
    }
    if (idx >= WPACK_SZ) return;
    if (idx < OFF_W2T) {                          // W1t [256][128]
        int j = idx >> 7, k = idx & 127;
        wp[idx] = (f16)We1[k * 256 + j];
    } else if (idx < OFF_WE3H) {                  // W2t [128][256]
        int t = idx - OFF_W2T;
        int j = t >> 8, k = t & 255;
        wp[idx] = (f16)We2[k * 128 + j];
    } else if (idx < OFF_RI0) {                   // We3h copy
        wp[idx] = (f16)We3[idx - OFF_WE3H];
    } else if (idx < OFF_RI1) {                   // Ri0 [128][96]
        int t = idx - OFF_RI0;
        int n = t / 96, c = t % 96;
        wp[idx] = (f16)Wi0[c * 128 + n];
    } else if (idx < OFF_RI2) {                   // Ri1 [256][128]
        int t = idx - OFF_RI1;
        int n = t >> 7, k = t & 127;
        wp[idx] = (f16)Wi1[k * 256 + n];
    } else if (idx < OFF_RI3) {                   // Ri2 [128][256]
        int t = idx - OFF_RI2;
        int n = t >> 8, k = t & 255;
        wp[idx] = (f16)Wi2[k * 128 + n];
    } else if (idx < OFF_RJ0) {                   // Ri3 [32][128]
        int t = idx - OFF_RI3;
        int n = t >> 7, k = t & 127;
        wp[idx] = (f16)Wi3[k * 32 + n];
    } else if (idx < OFF_RJ1) {                   // Rj0 [128][64]
        int t = idx - OFF_RJ0;
        int n = t >> 6, c = t & 63;
        wp[idx] = (f16)Wj0[c * 128 + n];
    } else if (idx < OFF_RJ2) {                   // Rj1 [256][128]
        int t = idx - OFF_RJ1;
        int n = t >> 7, k = t & 127;
        wp[idx] = (f16)Wj1[k * 256 + n];
    } else if (idx < OFF_RJ3) {                   // Rj2 [128][256]
        int t = idx - OFF_RJ2;
        int n = t >> 8, k = t & 255;
        wp[idx] = (f16)Wj2[k * 128 + n];
    } else {                                      // Rj3 [32][128]
        int t = idx - OFF_RJ3;
        int n = t >> 7, k = t & 127;
        wp[idx] = (f16)Wj3[k * 32 + n];
    }
}

// ===================== task bodies (R6 kernels, arrays re-homed in union) ==

__device__ void edge_body(SmemU& su, int tid, int tile,
                          const float* __restrict__ am,
                          const float* __restrict__ We0,
                          const float* __restrict__ be0,
                          const f16* __restrict__ W1t,
                          const float* __restrict__ be1,
                          const f16* __restrict__ W2t,
                          const float* __restrict__ be2,
                          f16* __restrict__ f) {
    int lane = tid & 63, wv = tid >> 6;
    long long g0 = (long long)tile * 64;

    ((float*)su.e.xl)[tid] = am[g0 * 4 + tid];
    __syncthreads();

    {   // layer 1: K=4, VALU
        int j = tid & 127, e0 = (tid >> 7) * 32;
        float w0 = We0[j], w1 = We0[128 + j], w2 = We0[256 + j], w3 = We0[384 + j];
        float bb = be0[j];
        #pragma unroll 8
        for (int e = e0; e < e0 + 32; ++e) {
            float v = bb + su.e.xl[e][0] * w0 + su.e.xl[e][1] * w1
                         + su.e.xl[e][2] * w2 + su.e.xl[e][3] * w3;
            su.e.y1[e][j] = (f16)fmaxf(v, 0.f);
        }
    }
    __syncthreads();

    int m = lane & 15, q = lane >> 4;

    {   // layer 2
        f32x4 acc[4][4];
        #pragma unroll
        for (int ct = 0; ct < 4; ++ct)
            #pragma unroll
            for (int rt = 0; rt < 4; ++rt) acc[ct][rt] = (f32x4){0.f, 0.f, 0.f, 0.f};
        #pragma unroll
        for (int s = 0; s < 4; ++s) {
            int k0 = s * 32 + q * 8;
            f16x8 afr[4], bfr[4];
            #pragma unroll
            for (int rt = 0; rt < 4; ++rt)
                afr[rt] = *(const f16x8*)&su.e.y1[rt * 16 + m][k0];
            #pragma unroll
            for (int ct = 0; ct < 4; ++ct) {
                int n = (wv * 4 + ct) * 16 + m;
                bfr[ct] = *(const f16x8*)(W1t + n * 128 + k0);
            }
            #pragma unroll
            for (int ct = 0; ct < 4; ++ct)
                #pragma unroll
                for (int rt = 0; rt < 4; ++rt)
                    acc[ct][rt] = MFMA16(afr[rt], bfr[ct], acc[ct][rt]);
        }
        #pragma unroll
        for (int ct = 0; ct < 4; ++ct) {
            int n = (wv * 4 + ct) * 16 + m;
            float bb = be1[n];
            #pragma unroll
            for (int rt = 0; rt < 4; ++rt)
                #pragma unroll
                for (int r = 0; r < 4; ++r) {
                    int row = rt * 16 + q * 4 + r;
                    su.e.y2[row][n] = (f16)fmaxf(acc[ct][rt][r] + bb, 0.f);
                }
        }
    }
    __syncthreads();

    {   // layer 3 (out-stage back into y1)
        f32x4 acc[2][4];
        #pragma unroll
        for (int ct = 0; ct < 2; ++ct)
            #pragma unroll
            for (int rt = 0; rt < 4; ++rt) acc[ct][rt] = (f32x4){0.f, 0.f, 0.f, 0.f};
        #pragma unroll
        for (int s = 0; s < 8; ++s) {
            int k0 = s * 32 + q * 8;
            f16x8 afr[4], bfr[2];
            #pragma unroll
            for (int rt = 0; rt < 4; ++rt)
                afr[rt] = *(const f16x8*)&su.e.y2[rt * 16 + m][k0];
            #pragma unroll
            for (int ct = 0; ct < 2; ++ct) {
                int n = (wv * 2 + ct) * 16 + m;
                bfr[ct] = *(const f16x8*)(W2t + n * 256 + k0);
            }
            #pragma unroll
            for (int ct = 0; ct < 2; ++ct)
                #pragma unroll
                for (int rt = 0; rt < 4; ++rt)
                    acc[ct][rt] = MFMA16(afr[rt], bfr[ct], acc[ct][rt]);
        }
        #pragma unroll
        for (int ct = 0; ct < 2; ++ct) {
            int n = (wv * 2 + ct) * 16 + m;
            float bb = be2[n];
            #pragma unroll
            for (int rt = 0; rt < 4; ++rt)
                #pragma unroll
                for (int r = 0; r < 4; ++r) {
                    int row = rt * 16 + q * 4 + r;
                    su.e.y1[row][n] = (f16)fmaxf(acc[ct][rt][r] + bb, 0.f);
                }
        }
    }
    __syncthreads();

    #pragma unroll
    for (int j = 0; j < 4; ++j) {
        int c = tid + j * 256;
        int e = c >> 4, pp = c & 15;
        *(uint4*)(f + (g0 + e) * 128 + pp * 8) = *(const uint4*)&su.e.y1[e][pp * 8];
    }
}

__device__ void pgemm_body(SmemU& su, int tid, int ob, int nt,
                           const f16* __restrict__ h16,
                           const f16* __restrict__ We3h,
                           f16* __restrict__ P2) {
    int lane = tid & 63, wv = tid >> 6;

    #pragma unroll
    for (int j = 0; j < 4; ++j) {
        int c = tid + j * 256;
        int row = c >> 3, pp = c & 7;
        *(uint4*)&su.pg.Al[row][pp * 8] =
            *(const uint4*)(h16 + (size_t)(nt * 128 + row) * 64 + pp * 8);
    }
    #pragma unroll
    for (int j = 0; j < 4; ++j) {
        int c = tid + j * 256;
        int k = c >> 3, pp = c & 7;
        *(uint4*)&su.pg.Bl[k][pp * 8] =
            *(const uint4*)(We3h + ((size_t)(k * 64 + ob)) * 64 + pp * 8);
    }
    __syncthreads();

    int m = lane & 15, q = lane >> 4;
    f32x4 acc[2][8];
    #pragma unroll
    for (int ct = 0; ct < 2; ++ct)
        #pragma unroll
        for (int rt = 0; rt < 8; ++rt) acc[ct][rt] = (f32x4){0.f, 0.f, 0.f, 0.f};
    #pragma unroll
    for (int s = 0; s < 2; ++s) {
        int k0 = s * 32 + q * 8;
        f16x8 afr[8], bfr[2];
        #pragma unroll
        for (int rt = 0; rt < 8; ++rt)
            afr[rt] = *(const f16x8*)&su.pg.Al[rt * 16 + m][k0];
        #pragma unroll
        for (int ct = 0; ct < 2; ++ct)
            bfr[ct] = *(const f16x8*)&su.pg.Bl[(wv * 2 + ct) * 16 + m][k0];
        #pragma unroll
        for (int ct = 0; ct < 2; ++ct)
            #pragma unroll
            for (int rt = 0; rt < 8; ++rt)
                acc[ct][rt] = MFMA16(afr[rt], bfr[ct], acc[ct][rt]);
    }
    #pragma unroll
    for (int ct = 0; ct < 2; ++ct) {
        int col = (wv * 2 + ct) * 16 + m;
        #pragma unroll
        for (int rt = 0; rt < 8; ++rt)
            #pragma unroll
            for (int r = 0; r < 4; ++r)
                su.pg.Ol[rt * 16 + q * 4 + r][col] = (f16)acc[ct][rt][r];
    }
    __syncthreads();
    #pragma unroll
    for (int j = 0; j < 8; ++j) {
        int c = tid + j * 256;
        int row = c >> 4, pp = c & 15;
        *(uint4*)(P2 + ((size_t)(nt * 128 + row) * 64 + ob) * 128 + pp * 8) =
            *(const uint4*)&su.pg.Ol[row][pp * 8];
    }
}

// bias: biasb[b,o] = sum_i be3[o*64+i] * (sum_w h[b,w,i])
__device__ void bias_body(SmemU& su, int tid, int b,
                          const float* __restrict__ h,
                          const float* __restrict__ be3,
                          float* __restrict__ biasb) {
    int i = tid & 63, wq = tid >> 6;
    float s = 0.f;
    for (int w = wq; w < N; w += 4) s += h[((size_t)(b * N + w)) * H + i];
    su.bi.prt[wq][i] = s;
    __syncthreads();
    if (tid < 64)
        su.bi.hsum[tid] = su.bi.prt[0][tid] + su.bi.prt[1][tid]
                        + su.bi.prt[2][tid] + su.bi.prt[3][tid];
    __syncthreads();
    if (tid < 64) {
        float sb = 0.f;
        #pragma unroll 4
        for (int ii = 0; ii < H; ++ii) sb += be3[tid * H + ii] * su.bi.hsum[ii];
        biasb[b * 64 + tid] = sb;
    }
}

// -------------------------------------------------------------------------
// mega0: edge tiles (0..4095) + L0 p_gemm (4096..5119) + L0 bias (5120..5135)
__global__ __launch_bounds__(256, 2) void mega0_kernel(
    const float* __restrict__ am,
    const float* __restrict__ We0, const float* __restrict__ be0,
    const float* __restrict__ be1, const float* __restrict__ be2,
    const float* __restrict__ be3,
    const f16* __restrict__ wp,
    const float* __restrict__ h, const f16* __restrict__ h16,
    f16* __restrict__ f, f16* __restrict__ P2, float* __restrict__ biasb) {
    __shared__ SmemU su;
    int tid = threadIdx.x;
    int bid = blockIdx.x;
    if (bid < 4096) {
        edge_body(su, tid, bid, am, We0, be0, wp + OFF_W1T, be1, wp + OFF_W2T,
                  be2, f);
    } else if (bid < 5120) {
        int t = bid - 4096;
        pgemm_body(su, tid, t & 63, t >> 6, h16, wp + OFF_WE3H, P2);
    } else {
        bias_body(su, tid, bid - 5120, h, be3, biasb);
    }
}

// pg_bias: p_gemm (0..1023) + bias (1024..1039), for layers 1,2
__global__ __launch_bounds__(256, 2) void pg_bias_kernel(
    const float* __restrict__ be3, const f16* __restrict__ wp,
    const float* __restrict__ h, const f16* __restrict__ h16,
    f16* __restrict__ P2, float* __restrict__ biasb) {
    __shared__ SmemU su;
    int tid = threadIdx.x;
    int bid = blockIdx.x;
    if (bid < 1024) {
        pgemm_body(su, tid, bid & 63, bid >> 6, h16, wp + OFF_WE3H, P2);
    } else {
        bias_body(su, tid, bid - 1024, h, be3, biasb);
    }
}

// -------------------------------------------------------------------------
// msg GEMM: part[ws][(b,v),o] = sum_{w in split} sum_k f[(b,v),w,k]*P2[(b,w),o,k]
__global__ __launch_bounds__(256, 2) void msg_mfma(
    const f16* __restrict__ f, const f16* __restrict__ P2,
    float* __restrict__ part) {
    __shared__ f16 Al[128][136];
    __shared__ f16 Bl[64][136];
    int tid = threadIdx.x, lane = tid & 63, wv = tid >> 6;
    int ws = blockIdx.x;
    int b  = blockIdx.y;
    int m = lane & 15, q = lane >> 4;

    f32x4 acc[2][4];
    #pragma unroll
    for (int rt = 0; rt < 2; ++rt)
        #pragma unroll
        for (int ct = 0; ct < 4; ++ct) acc[rt][ct] = (f32x4){0.f, 0.f, 0.f, 0.f};

    for (int wi = 0; wi < 4; ++wi) {
        int w = ws * 4 + wi;
        #pragma unroll
        for (int j = 0; j < 8; ++j) {
            int c = tid + j * 256;
            int v = c >> 4, pp = c & 15;
            *(uint4*)&Al[v][pp * 8] =
                *(const uint4*)(f + (((size_t)(b * 128 + v) * 128 + w) * 128) + pp * 8);
        }
        #pragma unroll
        for (int j = 0; j < 4; ++j) {
            int c = tid + j * 256;
            int o = c >> 4, pp = c & 15;
            *(uint4*)&Bl[o][pp * 8] =
                *(const uint4*)(P2 + (((size_t)(b * 128 + w) * 64 + o) * 128) + pp * 8);
        }
        __syncthreads();
        #pragma unroll
        for (int s = 0; s < 4; ++s) {
            int k0 = s * 32 + q * 8;
            f16x8 afr[2], bfr[4];
            #pragma unroll
            for (int rt = 0; rt < 2; ++rt)
                afr[rt] = *(const f16x8*)&Al[(wv * 2 + rt) * 16 + m][k0];
            #pragma unroll
            for (int ct = 0; ct < 4; ++ct)
                bfr[ct] = *(const f16x8*)&Bl[ct * 16 + m][k0];
            #pragma unroll
            for (int rt = 0; rt < 2; ++rt)
                #pragma unroll
                for (int ct = 0; ct < 4; ++ct)
                    acc[rt][ct] = MFMA16(afr[rt], bfr[ct], acc[rt][ct]);
        }
        __syncthreads();
    }
    float* pp = part + (size_t)ws * (2048 * 64);
    #pragma unroll
    for (int rt = 0; rt < 2; ++rt)
        #pragma unroll
        for (int ct = 0; ct < 4; ++ct) {
            int o = ct * 16 + m;
            #pragma unroll
            for (int r = 0; r < 4; ++r) {
                int v = (wv * 2 + rt) * 16 + q * 4 + r;
                pp[(size_t)(b * 128 + v) * 64 + o] = acc[rt][ct][r];
            }
        }
}

// -------------------------------------------------------------------------
// GRU: msg = biasb[b] + sum of 32 partials; torch GRU step; mask; write h/h16.
__global__ __launch_bounds__(192) void gru_kernel(
    const float* __restrict__ biasb, const float* __restrict__ part,
    float* __restrict__ h, f16* __restrict__ h16,
    const float* __restrict__ Wih, const float* __restrict__ Whh,
    const float* __restrict__ bih, const float* __restrict__ bhh,
    const int* __restrict__ g_size) {
    __shared__ float m_lds[M];
    __shared__ float h_lds[H];
    __shared__ float gi[3 * H], gh[3 * H];
    int tid = threadIdx.x;
    int bv  = blockIdx.x;
    int b = bv >> 7, v = bv & 127;

    if (tid < M) {
        float s = biasb[b * 64 + tid];
        #pragma unroll 8
        for (int sp = 0; sp < 32; ++sp)
            s += part[(size_t)sp * (2048 * 64) + bv * 64 + tid];
        m_lds[tid] = s;
    } else if (tid < M + H) {
        h_lds[tid - M] = h[bv * H + (tid - M)];
    }
    __syncthreads();

    {
        float si = bih[tid], sh = bhh[tid];
        const float* wi = Wih + tid * M;
        const float* wh = Whh + tid * H;
        #pragma unroll 4
        for (int k = 0; k < M; ++k) si += wi[k] * m_lds[k];
        #pragma unroll 4
        for (int k = 0; k < H; ++k) sh += wh[k] * h_lds[k];
        gi[tid] = si;
        gh[tid] = sh;
    }
    __syncthreads();
    if (tid < H) {
        float r = 1.f / (1.f + expf(-(gi[tid] + gh[tid])));
        float z = 1.f / (1.f + expf(-(gi[H + tid] + gh[H + tid])));
        float n = tanhf(gi[2 * H + tid] + r * gh[2 * H + tid]);
        float hv = (1.f - z) * n + z * h_lds[tid];
        float maskf = (v < g_size[b]) ? 1.f : 0.f;
        hv *= maskf;
        h[bv * H + tid] = hv;
        h16[bv * H + tid] = (f16)hv;
    }
}

// -------------------------------------------------------------------------
// Readout via MFMA (R6-proven, unchanged)
__global__ __launch_bounds__(256, 4) void readout_mfma(
    const f16* __restrict__ h16, const f16* __restrict__ hin16,
    const int* __restrict__ g_size, const f16* __restrict__ wp,
    const float* __restrict__ bi0, const float* __restrict__ bi1,
    const float* __restrict__ bi2, const float* __restrict__ bi3,
    const float* __restrict__ bj0, const float* __restrict__ bj1,
    const float* __restrict__ bj2, const float* __restrict__ bj3,
    float* __restrict__ contrib) {
    __shared__ f16 Xl[32][104];
    __shared__ f16 A1[32][136];
    __shared__ f16 A2[32][264];
    __shared__ float Gl[32][36];
    const f16* Ri0 = wp + OFF_RI0; const f16* Ri1 = wp + OFF_RI1;
    const f16* Ri2 = wp + OFF_RI2; const f16* Ri3 = wp + OFF_RI3;
    const f16* Rj0 = wp + OFF_RJ0; const f16* Rj1 = wp + OFF_RJ1;
    const f16* Rj2 = wp + OFF_RJ2; const f16* Rj3 = wp + OFF_RJ3;
    int tid = threadIdx.x, lane = tid & 63, wv = tid >> 6;
    int m = lane & 15, q = lane >> 4;
    int r0 = blockIdx.x * 32;

    {
        int row = tid >> 3, pp = tid & 7;
        *(uint4*)&Xl[row][pp * 8] = *(const uint4*)(h16 + (size_t)(r0 + row) * 64 + pp * 8);
        if (tid < 128) {
            int row2 = tid >> 2, p2 = tid & 3;
            *(uint4*)&Xl[row2][64 + p2 * 8] =
                *(const uint4*)(hin16 + (size_t)(r0 + row2) * 32 + p2 * 8);
        }
    }
    __syncthreads();

    // i-chain L0
    {
        f32x4 acc[2][2];
        #pragma unroll
        for (int ct = 0; ct < 2; ++ct)
            #pragma unroll
            for (int rt = 0; rt < 2; ++rt) acc[ct][rt] = (f32x4){0.f, 0.f, 0.f, 0.f};
        #pragma unroll
        for (int s = 0; s < 3; ++s) {
            int k0 = s * 32 + q * 8;
            f16x8 afr[2], bfr[2];
            #pragma unroll
            for (int rt = 0; rt < 2; ++rt) afr[rt] = *(const f16x8*)&Xl[rt * 16 + m][k0];
            #pragma unroll
            for (int ct = 0; ct < 2; ++ct)
                bfr[ct] = *(const f16x8*)(Ri0 + ((wv * 2 + ct) * 16 + m) * 96 + k0);
            #pragma unroll
            for (int ct = 0; ct < 2; ++ct)
                #pragma unroll
                for (int rt = 0; rt < 2; ++rt)
                    acc[ct][rt] = MFMA16(afr[rt], bfr[ct], acc[ct][rt]);
        }
        #pragma unroll
        for (int ct = 0; ct < 2; ++ct) {
            int n = (wv * 2 + ct) * 16 + m;
            float bb = bi0[n];
            #pragma unroll
            for (int rt = 0; rt < 2; ++rt)
                #pragma unroll
                for (int r = 0; r < 4; ++r)
                    A1[rt * 16 + q * 4 + r][n] = (f16)fmaxf(acc[ct][rt][r] + bb, 0.f);
        }
    }
    __syncthreads();

    // i-chain L1
    {
        f32x4 acc[4][2];
        #pragma unroll
        for (int ct = 0; ct < 4; ++ct)
            #pragma unroll
            for (int rt = 0; rt < 2; ++rt) acc[ct][rt] = (f32x4){0.f, 0.f, 0.f, 0.f};
        #pragma unroll
        for (int s = 0; s < 4; ++s) {
            int k0 = s * 32 + q * 8;
            f16x8 afr[2], bfr[4];
            #pragma unroll
            for (int rt = 0; rt < 2; ++rt) afr[rt] = *(const f16x8*)&A1[rt * 16 + m][k0];
            #pragma unroll
            for (int ct = 0; ct < 4; ++ct)
                bfr[ct] = *(const f16x8*)(Ri1 + ((wv * 4 + ct) * 16 + m) * 128 + k0);
            #pragma unroll
            for (int ct = 0; ct < 4; ++ct)
                #pragma unroll
                for (int rt = 0; rt < 2; ++rt)
                    acc[ct][rt] = MFMA16(afr[rt], bfr[ct], acc[ct][rt]);
        }
        #pragma unroll
        for (int ct = 0; ct < 4; ++ct) {
            int n = (wv * 4 + ct) * 16 + m;
            float bb = bi1[n];
            #pragma unroll
            for (int rt = 0; rt < 2; ++rt)
                #pragma unroll
                for (int r = 0; r < 4; ++r)
                    A2[rt * 16 + q * 4 + r][n] = (f16)fmaxf(acc[ct][rt][r] + bb, 0.f);
        }
    }
    __syncthreads();

    // i-chain L2
    {
        f32x4 acc[2][2];
        #pragma unroll
        for (int ct = 0; ct < 2; ++ct)
            #pragma unroll
            for (int rt = 0; rt < 2; ++rt) acc[ct][rt] = (f32x4){0.f, 0.f, 0.f, 0.f};
        #pragma unroll
        for (int s = 0; s < 8; ++s) {
            int k0 = s * 32 + q * 8;
            f16x8 afr[2], bfr[2];
            #pragma unroll
            for (int rt = 0; rt < 2; ++rt) afr[rt] = *(const f16x8*)&A2[rt * 16 + m][k0];
            #pragma unroll
            for (int ct = 0; ct < 2; ++ct)
                bfr[ct] = *(const f16x8*)(Ri2 + ((wv * 2 + ct) * 16 + m) * 256 + k0);
            #pragma unroll
            for (int ct = 0; ct < 2; ++ct)
                #pragma unroll
                for (int rt = 0; rt < 2; ++rt)
                    acc[ct][rt] = MFMA16(afr[rt], bfr[ct], acc[ct][rt]);
        }
        __syncthreads();
        #pragma unroll
        for (int ct = 0; ct < 2; ++ct) {
            int n = (wv * 2 + ct) * 16 + m;
            float bb = bi2[n];
            #pragma unroll
            for (int rt = 0; rt < 2; ++rt)
                #pragma unroll
                for (int r = 0; r < 4; ++r)
                    A1[rt * 16 + q * 4 + r][n] = (f16)fmaxf(acc[ct][rt][r] + bb, 0.f);
        }
    }
    __syncthreads();

    // i-chain L3 -> gate
    if (wv < 2) {
        f32x4 acc[2];
        acc[0] = (f32x4){0.f, 0.f, 0.f, 0.f};
        acc[1] = (f32x4){0.f, 0.f, 0.f, 0.f};
        int n = wv * 16 + m;
        #pragma unroll
        for (int s = 0; s < 4; ++s) {
            int k0 = s * 32 + q * 8;
            f16x8 bfr = *(const f16x8*)(Ri3 + n * 128 + k0);
            #pragma unroll
            for (int rt = 0; rt < 2; ++rt) {
                f16x8 afr = *(const f16x8*)&A1[rt * 16 + m][k0];
                acc[rt] = MFMA16(afr, bfr, acc[rt]);
            }
        }
        float bb = bi3[n];
        #pragma unroll
        for (int rt = 0; rt < 2; ++rt)
            #pragma unroll
            for (int r = 0; r < 4; ++r)
                Gl[rt * 16 + q * 4 + r][n] = 1.f / (1.f + expf(-(acc[rt][r] + bb)));
    }
    __syncthreads();

    // j-chain L0
    {
        f32x4 acc[2][2];
        #pragma unroll
        for (int ct = 0; ct < 2; ++ct)
            #pragma unroll
            for (int rt = 0; rt < 2; ++rt) acc[ct][rt] = (f32x4){0.f, 0.f, 0.f, 0.f};
        #pragma unroll
        for (int s = 0; s < 2; ++s) {
            int k0 = s * 32 + q * 8;
            f16x8 afr[2], bfr[2];
            #pragma unroll
            for (int rt = 0; rt < 2; ++rt) afr[rt] = *(const f16x8*)&Xl[rt * 16 + m][k0];
            #pragma unroll
            for (int ct = 0; ct < 2; ++ct)
                bfr[ct] = *(const f16x8*)(Rj0 + ((wv * 2 + ct) * 16 + m) * 64 + k0);
            #pragma unroll
            for (int ct = 0; ct < 2; ++ct)
                #pragma unroll
                for (int rt = 0; rt < 2; ++rt)
                    acc[ct][rt] = MFMA16(afr[rt], bfr[ct], acc[ct][rt]);
        }
        __syncthreads();
        #pragma unroll
        for (int ct = 0; ct < 2; ++ct) {
            int n = (wv * 2 + ct) * 16 + m;
            float bb = bj0[n];
            #pragma unroll
            for (int rt = 0; rt < 2; ++rt)
                #pragma unroll
                for (int r = 0; r < 4; ++r)
                    A1[rt * 16 + q * 4 + r][n] = (f16)fmaxf(acc[ct][rt][r] + bb, 0.f);
        }
    }
    __syncthreads();

    // j-chain L1
    {
        f32x4 acc[4][2];
        #pragma unroll
        for (int ct = 0; ct < 4; ++ct)
            #pragma unroll
            for (int rt = 0; rt < 2; ++rt) acc[ct][rt] = (f32x4){0.f, 0.f, 0.f, 0.f};
        #pragma unroll
        for (int s = 0; s < 4; ++s) {
            int k0 = s * 32 + q * 8;
            f16x8 afr[2], bfr[4];
            #pragma unroll
            for (int rt = 0; rt < 2; ++rt) afr[rt] = *(const f16x8*)&A1[rt * 16 + m][k0];
            #pragma unroll
            for (int ct = 0; ct < 4; ++ct)
                bfr[ct] = *(const f16x8*)(Rj1 + ((wv * 4 + ct) * 16 + m) * 128 + k0);
            #pragma unroll
            for (int ct = 0; ct < 4; ++ct)
                #pragma unroll
                for (int rt = 0; rt < 2; ++rt)
                    acc[ct][rt] = MFMA16(afr[rt], bfr[ct], acc[ct][rt]);
        }
        #pragma unroll
        for (int ct = 0; ct < 4; ++ct) {
            int n = (wv * 4 + ct) * 16 + m;
            float bb = bj1[n];
            #pragma unroll
            for (int rt = 0; rt < 2; ++rt)
                #pragma unroll
                for (int r = 0; r < 4; ++r)
                    A2[rt * 16 + q * 4 + r][n] = (f16)fmaxf(acc[ct][rt][r] + bb, 0.f);
        }
    }
    __syncthreads();

    // j-chain L2
    {
        f32x4 acc[2][2];
        #pragma unroll
        for (int ct = 0; ct < 2; ++ct)
            #pragma unroll
            for (int rt = 0; rt < 2; ++rt) acc[ct][rt] = (f32x4){0.f, 0.f, 0.f, 0.f};
        #pragma unroll
        for (int s = 0; s < 8; ++s) {
            int k0 = s * 32 + q * 8;
            f16x8 afr[2], bfr[2];
            #pragma unroll
            for (int rt = 0; rt < 2; ++rt) afr[rt] = *(const f16x8*)&A2[rt * 16 + m][k0];
            #pragma unroll
            for (int ct = 0; ct < 2; ++ct)
                bfr[ct] = *(const f16x8*)(Rj2 + ((wv * 2 + ct) * 16 + m) * 256 + k0);
            #pragma unroll
            for (int ct = 0; ct < 2; ++ct)
                #pragma unroll
                for (int rt = 0; rt < 2; ++rt)
                    acc[ct][rt] = MFMA16(afr[rt], bfr[ct], acc[ct][rt]);
        }
        __syncthreads();
        #pragma unroll
        for (int ct = 0; ct < 2; ++ct) {
            int n = (wv * 2 + ct) * 16 + m;
            float bb = bj2[n];
            #pragma unroll
            for (int rt = 0; rt < 2; ++rt)
                #pragma unroll
                for (int r = 0; r < 4; ++r)
                    A1[rt * 16 + q * 4 + r][n] = (f16)fmaxf(acc[ct][rt][r] + bb, 0.f);
        }
    }
    __syncthreads();

    // j-chain L3 + combine
    if (wv < 2) {
        f32x4 acc[2];
        acc[0] = (f32x4){0.f, 0.f, 0.f, 0.f};
        acc[1] = (f32x4){0.f, 0.f, 0.f, 0.f};
        int n = wv * 16 + m;
        #pragma unroll
        for (int s = 0; s < 4; ++s) {
            int k0 = s * 32 + q * 8;
            f16x8 bfr = *(const f16x8*)(Rj3 + n * 128 + k0);
            #pragma unroll
            for (int rt = 0; rt < 2; ++rt) {
                f16x8 afr = *(const f16x8*)&A1[rt * 16 + m][k0];
                acc[rt] = MFMA16(afr, bfr, acc[rt]);
            }
        }
        float bb = bj3[n];
        #pragma unroll
        for (int rt = 0; rt < 2; ++rt)
            #pragma unroll
            for (int r = 0; r < 4; ++r) {
                int row = rt * 16 + q * 4 + r;
                int rg = r0 + row;
                int b = rg >> 7, v = rg & 127;
                float maskf = (v < g_size[b]) ? 1.f : 0.f;
                contrib[(size_t)rg * T + n] = maskf * Gl[row][n] * (acc[rt][r] + bb);
            }
    }
}

// -------------------------------------------------------------------------
__global__ __launch_bounds__(64) void finalize_kernel(const float* __restrict__ contrib,
                                                      float* __restrict__ out) {
    __shared__ float res[T];
    int b = blockIdx.x;
    int o = threadIdx.x;
    if (o < T) {
        float s = 0.f;
        for (int v = 0; v < N; ++v) s += contrib[(b * N + v) * T + o];
        res[o] = s;
    }
    __syncthreads();
    if (o < T) {
        float mx = res[0];
        for (int i = 1; i < T; ++i) mx = fmaxf(mx, res[i]);
        float se = 0.f;
        for (int i = 0; i < T; ++i) se += expf(res[i] - mx);
        out[b * T + o] = res[o] - mx - logf(se);
    }
}

// -------------------------------------------------------------------------
extern "C" void kernel_launch(void* const* d_in, const int* in_sizes, int n_in,
                              void* d_out, int out_size, void* d_ws, size_t ws_size,
                              hipStream_t stream) {
    (void)in_sizes; (void)n_in; (void)out_size; (void)ws_size;
    const float* h_in = (const float*)d_in[0];
    const float* am   = (const float*)d_in[1];
    const int*   g_sz = (const int*)d_in[2];
    const float* We0 = (const float*)d_in[3],  *be0 = (const float*)d_in[4];
    const float* We1 = (const float*)d_in[5],  *be1 = (const float*)d_in[6];
    const float* We2 = (const float*)d_in[7],  *be2 = (const float*)d_in[8];
    const float* We3 = (const float*)d_in[9],  *be3 = (const float*)d_in[10];
    const float* Wih = (const float*)d_in[11], *Whh = (const float*)d_in[12];
    const float* bih = (const float*)d_in[13], *bhh = (const float*)d_in[14];
    const float* Wi0 = (const float*)d_in[15], *bi0 = (const float*)d_in[16];
    const float* Wj0 = (const float*)d_in[17], *bj0 = (const float*)d_in[18];
    const float* Wi1 = (const float*)d_in[19], *bi1 = (const float*)d_in[20];
    const float* Wj1 = (const float*)d_in[21], *bj1 = (const float*)d_in[22];
    const float* Wi2 = (const float*)d_in[23], *bi2 = (const float*)d_in[24];
    const float* Wj2 = (const float*)d_in[25], *bj2 = (const float*)d_in[26];
    const float* Wi3 = (const float*)d_in[27], *bi3 = (const float*)d_in[28];
    const float* Wj3 = (const float*)d_in[29], *bj3 = (const float*)d_in[30];

    float* out = (float*)d_out;

    // workspace layout (~115 MB)
    f16*   f    = (f16*)d_ws;                             // 33554432 halves
    f16*   P2   = f + (size_t)33554432;                   // 16777216 halves
    float* part = (float*)(P2 + (size_t)16777216);        // 4194304 floats
    float* h    = part + (size_t)4194304;                 // 131072
    float* biasb = h + 131072;                            // 1024
    float* contrib = biasb + 1024;                        // 65536
    f16*   h16  = (f16*)(contrib + 65536);                // 131072 halves
    f16*   hin16 = h16 + 131072;                          // 65536 halves
    f16*   wp   = hin16 + 65536;                          // 749568 halves

    prep_kernel<<<(WPACK_SZ + 255) / 256, 256, 0, stream>>>(
        h_in, We1, We2, We3, Wi0, Wi1, Wi2, Wi3, Wj0, Wj1, Wj2, Wj3,
        h, h16, hin16, wp);

    // layer 0: edge + p_gemm + bias fused into one launch
    mega0_kernel<<<4096 + 1024 + 16, 256, 0, stream>>>(
        am, We0, be0, be1, be2, be3, wp, h, h16, f, P2, biasb);
    msg_mfma<<<dim3(32, 16), 256, 0, stream>>>(f, P2, part);
    gru_kernel<<<B * N, 192, 0, stream>>>(biasb, part, h, h16,
                                          Wih, Whh, bih, bhh, g_sz);

    for (int l = 1; l < 3; ++l) {
        pg_bias_kernel<<<1024 + 16, 256, 0, stream>>>(be3, wp, h, h16, P2, biasb);
        msg_mfma<<<dim3(32, 16), 256, 0, stream>>>(f, P2, part);
        gru_kernel<<<B * N, 192, 0, stream>>>(biasb, part, h, h16,
                                              Wih, Whh, bih, bhh, g_sz);
    }

    readout_mfma<<<64, 256, 0, stream>>>(h16, hin16, g_sz, wp,
                                         bi0, bi1, bi2, bi3,
                                         bj0, bj1, bj2, bj3, contrib);
    finalize_kernel<<<B, 64, 0, stream>>>(contrib, out);
}